// Round 1
// baseline (2665.035 us; speedup 1.0000x reference)
//
#include <hip/hip_runtime.h>
#include <math.h>

#define BATCH 4
// D=256, HEADS=8, HD=32, L=3, P=4, FF=1024

// ---------------------------------------------------------------------------
// Depthwise 3x3 conv + bias (SAME padding). x: [B,256,H,W] -> y same shape.
__global__ __launch_bounds__(256)
void dwconv_kernel(const float* __restrict__ x, const float* __restrict__ wgt,
                   const float* __restrict__ bias, float* __restrict__ y,
                   int H, int W, int total)
{
    int idx = blockIdx.x * 256 + threadIdx.x;
    if (idx >= total) return;
    const int S = H * W;
    const int s = idx % S;
    const int bc = idx / S;          // b*256 + c
    const int c = bc & 255;
    const int i = s / W, j = s % W;
    const float* wp = wgt + c * 9;
    const float* xp = x + (long)bc * S;
    float acc = bias[c];
    #pragma unroll
    for (int dy = 0; dy < 3; ++dy) {
        const int ii = i + dy - 1;
        if (ii < 0 || ii >= H) continue;
        #pragma unroll
        for (int dx = 0; dx < 3; ++dx) {
            const int jj = j + dx - 1;
            if (jj < 0 || jj >= W) continue;
            acc = fmaf(xp[ii * W + jj], wp[dy * 3 + dx], acc);
        }
    }
    y[idx] = acc;
}

// ---------------------------------------------------------------------------
// Generic tiled fp32 GEMM: C[M,N] = epilogue(A[M,K] @ W[K,N]).
// BM=BN=128, BK=8, 256 threads, 8x8 per thread (split 4+4 rows/cols for
// conflict-free LDS reads).
// ACT: 0 none, 1 gelu(exact), 2 relu, 3 tanh
// BIASMODE: 0 none, 1 per-N, 2 per-M
// RESID: add R[m*ldr+n] after activation
// REMAP: scatter rows into concat layout: row = (mg/outQ)*outTot + outOff + mg%outQ
template<int ACT, int BIASMODE, bool RESID, bool REMAP>
__global__ __launch_bounds__(256)
void gemm_f32(const float* __restrict__ A, const float* __restrict__ W,
              const float* __restrict__ bias, const float* __restrict__ R,
              float* __restrict__ C,
              int M, int N, int K, int lda, int ldw, int ldc, int ldr,
              long aBS, long wBS, long cBS, long rBS,
              int outQ, int outTot, int outOff, int remapBase)
{
    __shared__ float As[8][128];
    __shared__ float Ws[8][128];
    const int tid = threadIdx.x;
    const int bz = blockIdx.z;
    A += bz * aBS; W += bz * wBS; C += bz * cBS;
    const float* Rp = R;
    if (RESID) Rp += bz * rBS;
    const int m0 = blockIdx.y * 128, n0 = blockIdx.x * 128;
    const int tx = tid & 15, ty = tid >> 4;
    const int lm = tid >> 1, lk = (tid & 1) << 2;     // A tile: row, k-start
    const int wk = tid >> 5, wn = (tid & 31) << 2;    // W tile: k, n-start
    float acc[8][8];
    #pragma unroll
    for (int i = 0; i < 8; ++i)
        #pragma unroll
        for (int j = 0; j < 8; ++j) acc[i][j] = 0.f;

    for (int k0 = 0; k0 < K; k0 += 8) {
        float4 av; av.x = av.y = av.z = av.w = 0.f;
        if (m0 + lm < M)
            av = *(const float4*)&A[(long)(m0 + lm) * lda + (k0 + lk)];
        float4 wv; wv.x = wv.y = wv.z = wv.w = 0.f;
        {
            const float* wrow = &W[(long)(k0 + wk) * ldw];
            const int n = n0 + wn;
            if (n + 3 < N) wv = *(const float4*)&wrow[n];
            else {
                if (n + 0 < N) wv.x = wrow[n + 0];
                if (n + 1 < N) wv.y = wrow[n + 1];
                if (n + 2 < N) wv.z = wrow[n + 2];
                if (n + 3 < N) wv.w = wrow[n + 3];
            }
        }
        __syncthreads();
        As[lk + 0][lm] = av.x; As[lk + 1][lm] = av.y;
        As[lk + 2][lm] = av.z; As[lk + 3][lm] = av.w;
        *(float4*)&Ws[wk][wn] = wv;
        __syncthreads();
        #pragma unroll
        for (int kk = 0; kk < 8; ++kk) {
            float a[8], b[8];
            *(float4*)&a[0] = *(const float4*)&As[kk][ty * 4];
            *(float4*)&a[4] = *(const float4*)&As[kk][64 + ty * 4];
            *(float4*)&b[0] = *(const float4*)&Ws[kk][tx * 4];
            *(float4*)&b[4] = *(const float4*)&Ws[kk][64 + tx * 4];
            #pragma unroll
            for (int i = 0; i < 8; ++i)
                #pragma unroll
                for (int j = 0; j < 8; ++j)
                    acc[i][j] = fmaf(a[i], b[j], acc[i][j]);
        }
    }

    #pragma unroll
    for (int i = 0; i < 8; ++i) {
        const int rI = (i < 4) ? (ty * 4 + i) : (64 + ty * 4 + i - 4);
        const int m = m0 + rI;
        if (m >= M) continue;
        long crow = m;
        if (REMAP) {
            const int mg = m + remapBase;
            const int bb = mg / outQ;
            const int qi = mg - bb * outQ;
            crow = (long)bb * outTot + outOff + qi;
        }
        #pragma unroll
        for (int j = 0; j < 8; ++j) {
            const int cJ = (j < 4) ? (tx * 4 + j) : (64 + tx * 4 + j - 4);
            const int n = n0 + cJ;
            if (n >= N) continue;
            float v = acc[i][j];
            if (BIASMODE == 1) v += bias[n];
            if (BIASMODE == 2) v += bias[m];
            if (ACT == 1) v = 0.5f * v * (1.f + erff(v * 0.70710678118654752f));
            if (ACT == 2) v = fmaxf(v, 0.f);
            if (ACT == 3) v = tanhf(v);
            if (RESID) v += Rp[(long)m * ldr + n];
            C[crow * ldc + n] = v;
        }
    }
}

// ---------------------------------------------------------------------------
// NCHW -> NHWC transpose: in [B,256,S] -> out [B,S,256]
__global__ __launch_bounds__(256)
void transpose_kernel(const float* __restrict__ in, float* __restrict__ out, int S)
{
    __shared__ float t[32][33];
    const int b = blockIdx.z;
    const int s0 = blockIdx.x * 32, c0 = blockIdx.y * 32;
    const int x = threadIdx.x, y = threadIdx.y;
    #pragma unroll
    for (int i = y; i < 32; i += 8) {
        const int s = s0 + x;
        t[i][x] = (s < S) ? in[((long)b * 256 + (c0 + i)) * S + s] : 0.f;
    }
    __syncthreads();
    #pragma unroll
    for (int i = y; i < 32; i += 8) {
        const int s = s0 + i;
        if (s < S) out[((long)b * S + s) * 256 + (c0 + x)] = t[x][i];
    }
}

// ---------------------------------------------------------------------------
// LayerNorm over last dim (256), one token per 256-thread block.
// addPos: add 2D sincos positional embedding + level embedding.
__global__ __launch_bounds__(256)
void ln_kernel(const float* __restrict__ x, const float* __restrict__ gamma,
               const float* __restrict__ beta, const float* __restrict__ lvlEmb,
               float* __restrict__ out, int Q, int Wq, int addPos)
{
    const int m = blockIdx.x;        // b*Q + qi
    const int c = threadIdx.x;
    const int qi = m % Q;
    const float v = x[(long)m * 256 + c];
    float s = v, s2 = v * v;
    #pragma unroll
    for (int o = 32; o > 0; o >>= 1) {
        s  += __shfl_down(s, o, 64);
        s2 += __shfl_down(s2, o, 64);
    }
    __shared__ float red[8];
    const int wid = c >> 6;
    if ((c & 63) == 0) { red[wid] = s; red[wid + 4] = s2; }
    __syncthreads();
    const float sum = red[0] + red[1] + red[2] + red[3];
    const float sq  = red[4] + red[5] + red[6] + red[7];
    const float mean = sum * (1.f / 256.f);
    const float var = sq * (1.f / 256.f) - mean * mean;
    const float rstd = 1.f / sqrtf(var + 1e-5f);
    float y = (v - mean) * rstd * gamma[c] + beta[c];
    if (addPos) {
        const int j = c & 63;
        const float denom = exp2f((float)j * (13.287712379549449f / 64.f)); // 10000^(j/64)
        const float coord = (c < 128) ? (float)(qi / Wq) : (float)(qi % Wq);
        const float ang = coord / denom;
        const float pv = ((c & 64) == 0) ? sinf(ang) : cosf(ang);
        y += pv + lvlEmb[c];
    }
    out[(long)m * 256 + c] = y;
}

// ---------------------------------------------------------------------------
// Softmax over groups of 12 (L*P), in place. One thread per (token, head).
__global__ __launch_bounds__(256)
void softmax12_kernel(float* __restrict__ a, int total)
{
    const int t = blockIdx.x * 256 + threadIdx.x;
    if (t >= total) return;
    float* p = a + (long)t * 12;
    float v[12];
    float mx = -1e30f;
    #pragma unroll
    for (int k = 0; k < 12; ++k) { v[k] = p[k]; mx = fmaxf(mx, v[k]); }
    float sum = 0.f;
    #pragma unroll
    for (int k = 0; k < 12; ++k) { v[k] = expf(v[k] - mx); sum += v[k]; }
    const float inv = 1.f / sum;
    #pragma unroll
    for (int k = 0; k < 12; ++k) p[k] = v[k] * inv;
}

// ---------------------------------------------------------------------------
// Deformable-attention sampling. One block per (b, query); 256 threads =
// 8 heads x 32 channels. Feature maps are NHWC [B, S, 256] so each corner
// read is 32 consecutive floats per head. Writes agg [M, 256] (token-major,
// ready to be the A operand of the output projection GEMM).
__global__ __launch_bounds__(256)
void sample_kernel(const float* __restrict__ off, const float* __restrict__ aw,
                   const float* __restrict__ f0, const float* __restrict__ f1,
                   const float* __restrict__ f2, float* __restrict__ agg,
                   int Q, int Wq, int Hq)
{
    const int m = blockIdx.x;            // b*Q + qi
    const int tid = threadIdx.x;
    const int h = tid >> 5, d = tid & 31;
    const int qi = m % Q, b = m / Q;
    __shared__ float soff[192];
    __shared__ float saw[96];
    if (tid < 192) soff[tid] = off[(long)m * 192 + tid];
    if (tid < 96)  saw[tid]  = aw[(long)m * 96 + tid];
    __syncthreads();
    const float refx = 2.f * ((float)(qi % Wq) + 0.5f) / (float)Wq - 1.f;
    const float refy = 2.f * ((float)(qi / Wq) + 0.5f) / (float)Hq - 1.f;
    const float* fps[3] = {f0, f1, f2};
    const int DIMS[3] = {80, 40, 20};
    float acc = 0.f;
    #pragma unroll
    for (int lvl = 0; lvl < 3; ++lvl) {
        const int Ws = DIMS[lvl], Hs = DIMS[lvl];
        const float* fp = fps[lvl] + ((long)b * Hs * Ws) * 256 + (h * 32 + d);
        #pragma unroll
        for (int p = 0; p < 4; ++p) {
            const float dx = soff[h * 24 + lvl * 8 + p * 2 + 0];
            const float dy = soff[h * 24 + lvl * 8 + p * 2 + 1];
            const float wa = saw[h * 12 + lvl * 4 + p];
            const float xx = (refx + dx + 1.f) * 0.5f * (float)(Ws - 1);
            const float yy = (refy + dy + 1.f) * 0.5f * (float)(Hs - 1);
            const float x0f = floorf(xx), y0f = floorf(yy);
            const float wx1 = xx - x0f, wy1 = yy - y0f;
            const float wx0 = 1.f - wx1, wy0 = 1.f - wy1;
            const int x0 = (int)x0f, y0 = (int)y0f;
            const bool vx0 = (x0 >= 0) && (x0 < Ws);
            const bool vx1 = (x0 + 1 >= 0) && (x0 + 1 < Ws);
            const bool vy0 = (y0 >= 0) && (y0 < Hs);
            const bool vy1 = (y0 + 1 >= 0) && (y0 + 1 < Hs);
            float v = 0.f;
            if (vy0) {
                const long rb = (long)(y0 * Ws) * 256;
                const float w00 = wx0 * wy0, w10 = wx1 * wy0;
                if (vx0 && w00 != 0.f) v += w00 * fp[rb + (long)x0 * 256];
                if (vx1 && w10 != 0.f) v += w10 * fp[rb + (long)(x0 + 1) * 256];
            }
            if (vy1) {
                const long rb = (long)((y0 + 1) * Ws) * 256;
                const float w01 = wx0 * wy1, w11 = wx1 * wy1;
                if (vx0 && w01 != 0.f) v += w01 * fp[rb + (long)x0 * 256];
                if (vx1 && w11 != 0.f) v += w11 * fp[rb + (long)(x0 + 1) * 256];
            }
            acc += wa * v;
        }
    }
    agg[(long)m * 256 + tid] = acc;
}

// ---------------------------------------------------------------------------
extern "C" void kernel_launch(void* const* d_in, const int* in_sizes, int n_in,
                              void* d_out, int out_size, void* d_ws, size_t ws_size,
                              hipStream_t stream)
{
    const float* feat[3] = {(const float*)d_in[0], (const float*)d_in[1], (const float*)d_in[2]};
    const float* dw_w  = (const float*)d_in[3];
    const float* dw_b  = (const float*)d_in[4];
    const float* pw_w  = (const float*)d_in[5];
    const float* pw_b  = (const float*)d_in[6];
    const float* off_w = (const float*)d_in[7];
    const float* off_b = (const float*)d_in[8];
    const float* aw_w  = (const float*)d_in[9];
    const float* aw_b  = (const float*)d_in[10];
    const float* op_w  = (const float*)d_in[11];
    const float* op_b  = (const float*)d_in[12];
    const float* nq_g  = (const float*)d_in[13];
    const float* nq_b  = (const float*)d_in[14];
    const float* nf_g  = (const float*)d_in[15];
    const float* nf_b  = (const float*)d_in[16];
    const float* ff1_w = (const float*)d_in[17];
    const float* ff1_b = (const float*)d_in[18];
    const float* ff2_w = (const float*)d_in[19];
    const float* ff2_b = (const float*)d_in[20];
    const float* lvl_e = (const float*)d_in[21];
    float* outp = (float*)d_out;

    const int DIMS[3]   = {80, 40, 20};
    const int SS[3]     = {6400, 1600, 400};
    const int tokOff[3] = {0, 6400, 8000};
    long attnBase[3];
    attnBase[0] = (long)BATCH * 8400 * 256;
    attnBase[1] = attnBase[0] + (long)BATCH * 6400 * 96;
    attnBase[2] = attnBase[1] + (long)BATCH * 1600 * 96;

    // workspace layout (floats); total ~41.4M floats (~166 MB)
    float* w = (float*)d_ws;
    float* nhwc[3];
    nhwc[0] = w;                                   // 4*6400*256
    nhwc[1] = nhwc[0] + (long)BATCH * 6400 * 256;  // 4*1600*256
    nhwc[2] = nhwc[1] + (long)BATCH * 1600 * 256;  // 4*400*256
    float* scrA = nhwc[2] + (long)BATCH * 400 * 256;  // 6,553,600 (dwconv y / FFN hidden chunk)
    float* scrB = scrA + (long)BATCH * 6400 * 256;    // 6,553,600 (pointwise out / offsets)
    float* qbuf = scrB + (long)BATCH * 6400 * 256;    // q / h
    float* tok1 = qbuf + (long)BATCH * 6400 * 256;    // tokens after attention
    float* aggb = tok1 + (long)BATCH * 6400 * 256;    // sampled aggregate

    // ---------------- Stage A: local branch per level ----------------
    for (int l = 0; l < 3; ++l) {
        const int H = DIMS[l], Wd = DIMS[l], S = SS[l];
        const int total = BATCH * 256 * S;
        dwconv_kernel<<<(total + 255) / 256, 256, 0, stream>>>(
            feat[l], dw_w + (long)l * 256 * 9, dw_b + l * 256, scrA, H, Wd, total);
        // pointwise: C[o,s] = gelu(pw_w[l] @ y + pw_b) + x   (per batch in z)
        dim3 g((S + 127) / 128, 2, BATCH);
        gemm_f32<1, 2, true, false><<<g, 256, 0, stream>>>(
            pw_w + (long)l * 256 * 256, scrA, pw_b + l * 256, feat[l], scrB,
            256, S, 256, 256, S, S, S,
            0L, (long)256 * S, (long)256 * S, (long)256 * S,
            0, 0, 0, 0);
        dim3 gt((S + 31) / 32, 8, BATCH);
        transpose_kernel<<<gt, dim3(32, 8, 1), 0, stream>>>(scrB, nhwc[l], S);
    }

    // ---------------- Stage B: per query level ----------------
    for (int l = 0; l < 3; ++l) {
        const int Wq = DIMS[l], Q = SS[l];
        const int M = BATCH * Q;
        float* attnP = outp + attnBase[l];

        // q = LN(tokens)*g+b + pos + lvl_emb
        ln_kernel<<<M, 256, 0, stream>>>(nhwc[l], nq_g, nq_b, lvl_e + l * 256,
                                         qbuf, Q, Wq, 1);
        // offsets = tanh(q @ off_w + off_b)  -> scrB [M,192]
        {
            dim3 g(2, (M + 127) / 128, 1);
            gemm_f32<3, 1, false, false><<<g, 256, 0, stream>>>(
                qbuf, off_w, off_b, nullptr, scrB,
                M, 192, 256, 256, 192, 192, 0,
                0L, 0L, 0L, 0L, 0, 0, 0, 0);
        }
        // attention logits -> d_out attn region [M,96]
        {
            dim3 g(1, (M + 127) / 128, 1);
            gemm_f32<0, 1, false, false><<<g, 256, 0, stream>>>(
                qbuf, aw_w, aw_b, nullptr, attnP,
                M, 96, 256, 256, 96, 96, 0,
                0L, 0L, 0L, 0L, 0, 0, 0, 0);
        }
        // softmax over L*P=12, in place
        {
            const int tot = M * 8;
            softmax12_kernel<<<(tot + 255) / 256, 256, 0, stream>>>(attnP, tot);
        }
        // deformable sampling -> aggb [M,256]
        sample_kernel<<<M, 256, 0, stream>>>(scrB, attnP, nhwc[0], nhwc[1], nhwc[2],
                                             aggb, Q, Wq, Wq);
        // tokens1 = tokens + agg @ op_w + op_b
        {
            dim3 g(2, (M + 127) / 128, 1);
            gemm_f32<0, 1, true, false><<<g, 256, 0, stream>>>(
                aggb, op_w, op_b, nhwc[l], tok1,
                M, 256, 256, 256, 256, 256, 256,
                0L, 0L, 0L, 0L, 0, 0, 0, 0);
        }
        // h = LN(tokens1)
        ln_kernel<<<M, 256, 0, stream>>>(tok1, nf_g, nf_b, nullptr, qbuf, Q, Wq, 0);
        // FFN in row chunks of 6400 (hidden buffer reuses scrA)
        for (int c0 = 0; c0 < M; c0 += 6400) {
            int Mc = M - c0; if (Mc > 6400) Mc = 6400;
            dim3 g1(8, (Mc + 127) / 128, 1);
            gemm_f32<2, 1, false, false><<<g1, 256, 0, stream>>>(
                qbuf + (long)c0 * 256, ff1_w, ff1_b, nullptr, scrA,
                Mc, 1024, 256, 256, 1024, 1024, 0,
                0L, 0L, 0L, 0L, 0, 0, 0, 0);
            dim3 g2(2, (Mc + 127) / 128, 1);
            gemm_f32<0, 1, true, true><<<g2, 256, 0, stream>>>(
                scrA, ff2_w, ff2_b, tok1 + (long)c0 * 256, outp,
                Mc, 256, 1024, 1024, 256, 256, 256,
                0L, 0L, 0L, 0L, Q, 8400, tokOff[l], c0);
        }
    }
}

// Round 3
// 1195.723 us; speedup vs baseline: 2.2288x; 2.2288x over previous
//
#include <hip/hip_runtime.h>
#include <math.h>

#define BATCH 4
// D=256, HEADS=8, HD=32, L=3, P=4, FF=1024

typedef short bf16x8 __attribute__((ext_vector_type(8)));
typedef float f32x4 __attribute__((ext_vector_type(4)));

__device__ __forceinline__ unsigned short f2b(float x) {
    union { float f; unsigned u; } v; v.f = x;
    unsigned r = v.u + 0x7FFFu + ((v.u >> 16) & 1u);
    return (unsigned short)(r >> 16);
}
__device__ __forceinline__ float b2f(unsigned short b) {
    union { unsigned u; float f; } v; v.u = ((unsigned)b) << 16; return v.f;
}

// ---------------------------------------------------------------------------
// Weight conversion: cast fp32 -> bf16 (same layout)
__global__ __launch_bounds__(256)
void cvt_cast_kernel(const float* __restrict__ in, unsigned short* __restrict__ out, int n)
{
    int i = blockIdx.x * 256 + threadIdx.x;
    if (i < n) out[i] = f2b(in[i]);
}

// Weight conversion: transpose [R][C] -> [C][R] with optional hi/lo split
__global__ __launch_bounds__(256)
void cvt_tr_kernel(const float* __restrict__ in, unsigned short* __restrict__ hi,
                   unsigned short* __restrict__ lo, int R, int C)
{
    int i = blockIdx.x * 256 + threadIdx.x;
    if (i >= R * C) return;
    int r = i / C, c = i - r * C;
    float v = in[i];
    unsigned short h = f2b(v);
    hi[(long)c * R + r] = h;
    if (lo) lo[(long)c * R + r] = f2b(v - b2f(h));
}

// ---------------------------------------------------------------------------
// Depthwise 3x3 conv + bias (SAME). x: [B,256,H,W] fp32 -> y fp32 same layout.
__global__ __launch_bounds__(256)
void dwconv_kernel(const float* __restrict__ x, const float* __restrict__ wgt,
                   const float* __restrict__ bias, float* __restrict__ y,
                   int H, int W, int total)
{
    int idx = blockIdx.x * 256 + threadIdx.x;
    if (idx >= total) return;
    const int S = H * W;
    const int s = idx % S;
    const int bc = idx / S;
    const int c = bc & 255;
    const int i = s / W, j = s % W;
    const float* wp = wgt + c * 9;
    const float* xp = x + (long)bc * S;
    float acc = bias[c];
    #pragma unroll
    for (int dy = 0; dy < 3; ++dy) {
        const int ii = i + dy - 1;
        if (ii < 0 || ii >= H) continue;
        #pragma unroll
        for (int dx = 0; dx < 3; ++dx) {
            const int jj = j + dx - 1;
            if (jj < 0 || jj >= W) continue;
            acc = fmaf(xp[ii * W + jj], wp[dy * 3 + dx], acc);
        }
    }
    y[idx] = acc;
}

// ---------------------------------------------------------------------------
// Fused transpose: y NCHW fp32 -> y_t [B,S,256] bf16 ; x NCHW fp32 -> x_t fp32
__global__ __launch_bounds__(256)
void transpose_pack_kernel(const float* __restrict__ y, const float* __restrict__ x,
                           unsigned short* __restrict__ yt, float* __restrict__ xt, int S)
{
    __shared__ float ty[32][33];
    __shared__ float txs[32][33];
    const int b = blockIdx.z;
    const int s0 = blockIdx.x * 32, c0 = blockIdx.y * 32;
    const int tx = threadIdx.x, tyi = threadIdx.y;
    #pragma unroll
    for (int i = tyi; i < 32; i += 8) {
        const int s = s0 + tx;
        if (s < S) {
            ty[i][tx]  = y[((long)b * 256 + (c0 + i)) * S + s];
            txs[i][tx] = x[((long)b * 256 + (c0 + i)) * S + s];
        }
    }
    __syncthreads();
    #pragma unroll
    for (int i = tyi; i < 32; i += 8) {
        const int s = s0 + i;
        if (s < S) {
            const long o = ((long)b * S + s) * 256 + (c0 + tx);
            yt[o] = f2b(ty[tx][i]);
            xt[o] = txs[tx][i];
        }
    }
}

// ---------------------------------------------------------------------------
// MFMA bf16 GEMM: C[M,N] = epilogue(A[M,K] @ Wt[N,K]^T)
// A: [M][K] bf16 (hi, + lo if SPLIT); Wt: [N][K] bf16 (hi, + lo if SPLIT)
// Tile 128x128, BK=32, 4 waves each computing 64x64 via 4x4 frags of 16x16x32.
// LDS: linear rows, stride 80 B (32 elems used + pad) -> 16B-aligned b128 ops,
// 2-way bank aliasing only (free). NO XOR swizzle (r2 bug: (row&7)<<4 mask
// overflows a 64B row -> rows 7/8 collide -> absmax 831).
// ACT: 0 none, 1 gelu(exact), 2 relu, 3 tanh. RESID adds fp32 R[m*ldr+n].
// REMAP scatters C rows into concat layout. OUTBF16 writes bf16 else fp32.
#define LROW 80  // bytes per LDS row
template<int ACT, bool SPLIT, bool RESID, bool REMAP, bool OUTBF16>
__global__ __launch_bounds__(256)
void gemm_mfma(const unsigned short* __restrict__ Ah, const unsigned short* __restrict__ Al,
               const unsigned short* __restrict__ Wh, const unsigned short* __restrict__ Wl,
               const float* __restrict__ bias, const float* __restrict__ Rr, int ldr,
               void* __restrict__ Cout, int M, int N, int K,
               int outQ, int outTot, int outOff, int remapBase)
{
    __shared__ char AsH[128 * LROW];
    __shared__ char WsH[128 * LROW];
    __shared__ char AsL[SPLIT ? 128 * LROW : 16];
    __shared__ char WsL[SPLIT ? 128 * LROW : 16];

    const int t = threadIdx.x;
    const int m0 = blockIdx.y * 128, n0 = blockIdx.x * 128;
    // staging: 2 threads per row, 16 bf16 (32B) each
    const int srow = t >> 1;
    const int sby = (t & 1) * 32;           // byte offset within row
    const bool aok = (m0 + srow) < M;
    const bool wok = (n0 + srow) < N;
    const long arow = (long)(m0 + srow) * K;
    const long wrow = (long)(n0 + srow) * K;
    char* aW  = AsH + srow * LROW + sby;
    char* wW  = WsH + srow * LROW + sby;
    char* aW2 = AsL + (SPLIT ? srow * LROW + sby : 0);
    char* wW2 = WsL + (SPLIT ? srow * LROW + sby : 0);

    const int lane = t & 63;
    const int wv = t >> 6;
    const int wm = (wv >> 1) * 64, wn = (wv & 1) * 64;
    const int fr = lane & 15, fg = lane >> 4;
    const int fby = fg << 4;                 // 16B chunk per k-group

    f32x4 acc[4][4];
    #pragma unroll
    for (int i = 0; i < 4; ++i)
        #pragma unroll
        for (int j = 0; j < 4; ++j) acc[i][j] = (f32x4){0.f, 0.f, 0.f, 0.f};

    for (int k0 = 0; k0 < K; k0 += 32) {
        const int kk = k0 + ((t & 1) << 4);
        uint4 va0 = {}, va1 = {}, vw0 = {}, vw1 = {};
        uint4 ua0 = {}, ua1 = {}, uw0 = {}, uw1 = {};
        if (aok) {
            const uint4* p = (const uint4*)(Ah + arow + kk);
            va0 = p[0]; va1 = p[1];
            if (SPLIT) { const uint4* q = (const uint4*)(Al + arow + kk); ua0 = q[0]; ua1 = q[1]; }
        }
        if (wok) {
            const uint4* p = (const uint4*)(Wh + wrow + kk);
            vw0 = p[0]; vw1 = p[1];
            if (SPLIT) { const uint4* q = (const uint4*)(Wl + wrow + kk); uw0 = q[0]; uw1 = q[1]; }
        }
        __syncthreads();
        *(uint4*)(aW)      = va0; *(uint4*)(aW + 16) = va1;
        *(uint4*)(wW)      = vw0; *(uint4*)(wW + 16) = vw1;
        if (SPLIT) {
            *(uint4*)(aW2)      = ua0; *(uint4*)(aW2 + 16) = ua1;
            *(uint4*)(wW2)      = uw0; *(uint4*)(wW2 + 16) = uw1;
        }
        __syncthreads();
        bf16x8 af[4], bfr[4];
        #pragma unroll
        for (int i = 0; i < 4; ++i) {
            const int ra = wm + i * 16 + fr;
            af[i]  = *(const bf16x8*)(AsH + ra * LROW + fby);
            const int rb = wn + i * 16 + fr;
            bfr[i] = *(const bf16x8*)(WsH + rb * LROW + fby);
        }
        if (!SPLIT) {
            #pragma unroll
            for (int mi = 0; mi < 4; ++mi)
                #pragma unroll
                for (int ni = 0; ni < 4; ++ni)
                    acc[mi][ni] = __builtin_amdgcn_mfma_f32_16x16x32_bf16(af[mi], bfr[ni], acc[mi][ni], 0, 0, 0);
        } else {
            bf16x8 al[4], bl[4];
            #pragma unroll
            for (int i = 0; i < 4; ++i) {
                const int ra = wm + i * 16 + fr;
                al[i] = *(const bf16x8*)(AsL + ra * LROW + fby);
                const int rb = wn + i * 16 + fr;
                bl[i] = *(const bf16x8*)(WsL + rb * LROW + fby);
            }
            #pragma unroll
            for (int mi = 0; mi < 4; ++mi)
                #pragma unroll
                for (int ni = 0; ni < 4; ++ni) {
                    acc[mi][ni] = __builtin_amdgcn_mfma_f32_16x16x32_bf16(af[mi], bfr[ni], acc[mi][ni], 0, 0, 0);
                    acc[mi][ni] = __builtin_amdgcn_mfma_f32_16x16x32_bf16(af[mi], bl[ni],  acc[mi][ni], 0, 0, 0);
                    acc[mi][ni] = __builtin_amdgcn_mfma_f32_16x16x32_bf16(al[mi], bfr[ni], acc[mi][ni], 0, 0, 0);
                }
        }
    }

    float* Cf = (float*)Cout;
    unsigned short* Cb = (unsigned short*)Cout;
    #pragma unroll
    for (int mi = 0; mi < 4; ++mi) {
        #pragma unroll
        for (int ni = 0; ni < 4; ++ni) {
            #pragma unroll
            for (int j = 0; j < 4; ++j) {
                const int m = m0 + wm + mi * 16 + fg * 4 + j;
                const int n = n0 + wn + ni * 16 + fr;
                if (m < M && n < N) {
                    float v = acc[mi][ni][j] + bias[n];
                    if (ACT == 1) v = 0.5f * v * (1.f + erff(v * 0.70710678118654752f));
                    if (ACT == 2) v = fmaxf(v, 0.f);
                    if (ACT == 3) v = tanhf(v);
                    if (RESID) v += Rr[(long)m * ldr + n];
                    long crow = m;
                    if (REMAP) {
                        const int mg = m + remapBase;
                        const int bb = mg / outQ;
                        const int qi = mg - bb * outQ;
                        crow = (long)bb * outTot + outOff + qi;
                    }
                    if (OUTBF16) Cb[crow * (long)N + n] = f2b(v);
                    else         Cf[crow * (long)N + n] = v;
                }
            }
        }
    }
}

// ---------------------------------------------------------------------------
// LayerNorm over last dim (256), one token per 256-thread block.
// OUTMODE 1: +pos+lvl_emb, write bf16 hi (o1) and lo (o2) split.
// OUTMODE 2: plain LN, write single bf16 (o1).
template<int OUTMODE>
__global__ __launch_bounds__(256)
void ln_kernel(const float* __restrict__ x, const float* __restrict__ gamma,
               const float* __restrict__ beta, const float* __restrict__ lvlEmb,
               unsigned short* __restrict__ o1, unsigned short* __restrict__ o2,
               int Q, int Wq)
{
    const int m = blockIdx.x;
    const int c = threadIdx.x;
    const int qi = m % Q;
    const float v = x[(long)m * 256 + c];
    float s = v, s2 = v * v;
    #pragma unroll
    for (int o = 32; o > 0; o >>= 1) {
        s  += __shfl_down(s, o, 64);
        s2 += __shfl_down(s2, o, 64);
    }
    __shared__ float red[8];
    const int wid = c >> 6;
    if ((c & 63) == 0) { red[wid] = s; red[wid + 4] = s2; }
    __syncthreads();
    const float sum = red[0] + red[1] + red[2] + red[3];
    const float sq  = red[4] + red[5] + red[6] + red[7];
    const float mean = sum * (1.f / 256.f);
    const float var = sq * (1.f / 256.f) - mean * mean;
    const float rstd = 1.f / sqrtf(var + 1e-5f);
    float y = (v - mean) * rstd * gamma[c] + beta[c];
    if (OUTMODE == 1) {
        const int j = c & 63;
        const float denom = exp2f((float)j * (13.287712379549449f / 64.f)); // 10000^(j/64)
        const float coord = (c < 128) ? (float)(qi / Wq) : (float)(qi % Wq);
        const float ang = coord / denom;
        const float pv = ((c & 64) == 0) ? sinf(ang) : cosf(ang);
        y += pv + lvlEmb[c];
        const unsigned short h = f2b(y);
        o1[(long)m * 256 + c] = h;
        o2[(long)m * 256 + c] = f2b(y - b2f(h));
    } else {
        o1[(long)m * 256 + c] = f2b(y);
    }
}

// ---------------------------------------------------------------------------
// Softmax over groups of 12 (L*P), in place (fp32, lives in d_out attn region).
__global__ __launch_bounds__(256)
void softmax12_kernel(float* __restrict__ a, int total)
{
    const int t = blockIdx.x * 256 + threadIdx.x;
    if (t >= total) return;
    float* p = a + (long)t * 12;
    float v[12];
    float mx = -1e30f;
    #pragma unroll
    for (int k = 0; k < 12; ++k) { v[k] = p[k]; mx = fmaxf(mx, v[k]); }
    float sum = 0.f;
    #pragma unroll
    for (int k = 0; k < 12; ++k) { v[k] = expf(v[k] - mx); sum += v[k]; }
    const float inv = 1.f / sum;
    #pragma unroll
    for (int k = 0; k < 12; ++k) p[k] = v[k] * inv;
}

// ---------------------------------------------------------------------------
// Deformable-attention sampling. One block per (b, query); 256 threads =
// 8 heads x 32 channels. Feature maps NHWC fp32 [B,S,256]. Writes agg bf16
// [M,256] (A operand of out-proj GEMM).
__global__ __launch_bounds__(256)
void sample_kernel(const float* __restrict__ off, const float* __restrict__ aw,
                   const float* __restrict__ f0, const float* __restrict__ f1,
                   const float* __restrict__ f2, unsigned short* __restrict__ agg,
                   int Q, int Wq, int Hq)
{
    const int m = blockIdx.x;
    const int tid = threadIdx.x;
    const int h = tid >> 5, d = tid & 31;
    const int qi = m % Q, b = m / Q;
    __shared__ float soff[192];
    __shared__ float saw[96];
    if (tid < 192) soff[tid] = off[(long)m * 192 + tid];
    if (tid < 96)  saw[tid]  = aw[(long)m * 96 + tid];
    __syncthreads();
    const float refx = 2.f * ((float)(qi % Wq) + 0.5f) / (float)Wq - 1.f;
    const float refy = 2.f * ((float)(qi / Wq) + 0.5f) / (float)Hq - 1.f;
    const float* fps[3] = {f0, f1, f2};
    const int DIMS[3] = {80, 40, 20};
    float acc = 0.f;
    #pragma unroll
    for (int lvl = 0; lvl < 3; ++lvl) {
        const int Ws = DIMS[lvl], Hs = DIMS[lvl];
        const float* fp = fps[lvl] + ((long)b * Hs * Ws) * 256 + (h * 32 + d);
        #pragma unroll
        for (int p = 0; p < 4; ++p) {
            const float dx = soff[h * 24 + lvl * 8 + p * 2 + 0];
            const float dy = soff[h * 24 + lvl * 8 + p * 2 + 1];
            const float wa = saw[h * 12 + lvl * 4 + p];
            const float xx = (refx + dx + 1.f) * 0.5f * (float)(Ws - 1);
            const float yy = (refy + dy + 1.f) * 0.5f * (float)(Hs - 1);
            const float x0f = floorf(xx), y0f = floorf(yy);
            const float wx1 = xx - x0f, wy1 = yy - y0f;
            const float wx0 = 1.f - wx1, wy0 = 1.f - wy1;
            const int x0 = (int)x0f, y0 = (int)y0f;
            const bool vx0 = (x0 >= 0) && (x0 < Ws);
            const bool vx1 = (x0 + 1 >= 0) && (x0 + 1 < Ws);
            const bool vy0 = (y0 >= 0) && (y0 < Hs);
            const bool vy1 = (y0 + 1 >= 0) && (y0 + 1 < Hs);
            float v = 0.f;
            if (vy0) {
                const long rb = (long)(y0 * Ws) * 256;
                const float w00 = wx0 * wy0, w10 = wx1 * wy0;
                if (vx0 && w00 != 0.f) v += w00 * fp[rb + (long)x0 * 256];
                if (vx1 && w10 != 0.f) v += w10 * fp[rb + (long)(x0 + 1) * 256];
            }
            if (vy1) {
                const long rb = (long)((y0 + 1) * Ws) * 256;
                const float w01 = wx0 * wy1, w11 = wx1 * wy1;
                if (vx0 && w01 != 0.f) v += w01 * fp[rb + (long)x0 * 256];
                if (vx1 && w11 != 0.f) v += w11 * fp[rb + (long)(x0 + 1) * 256];
            }
            acc += wa * v;
        }
    }
    agg[(long)m * 256 + tid] = f2b(acc);
}

// ---------------------------------------------------------------------------
extern "C" void kernel_launch(void* const* d_in, const int* in_sizes, int n_in,
                              void* d_out, int out_size, void* d_ws, size_t ws_size,
                              hipStream_t stream)
{
    (void)in_sizes; (void)n_in; (void)out_size; (void)ws_size;
    const float* feat[3] = {(const float*)d_in[0], (const float*)d_in[1], (const float*)d_in[2]};
    const float* dw_w  = (const float*)d_in[3];
    const float* dw_b  = (const float*)d_in[4];
    const float* pw_w  = (const float*)d_in[5];
    const float* pw_b  = (const float*)d_in[6];
    const float* off_w = (const float*)d_in[7];
    const float* off_b = (const float*)d_in[8];
    const float* aw_w  = (const float*)d_in[9];
    const float* aw_b  = (const float*)d_in[10];
    const float* op_w  = (const float*)d_in[11];
    const float* op_b  = (const float*)d_in[12];
    const float* nq_g  = (const float*)d_in[13];
    const float* nq_b  = (const float*)d_in[14];
    const float* nf_g  = (const float*)d_in[15];
    const float* nf_b  = (const float*)d_in[16];
    const float* ff1_w = (const float*)d_in[17];
    const float* ff1_b = (const float*)d_in[18];
    const float* ff2_w = (const float*)d_in[19];
    const float* ff2_b = (const float*)d_in[20];
    const float* lvl_e = (const float*)d_in[21];
    float* outp = (float*)d_out;

    const int DIMS[3]   = {80, 40, 20};
    const int SS[3]     = {6400, 1600, 400};
    const int tokOff[3] = {0, 6400, 8000};
    long attnBase[3];
    attnBase[0] = (long)BATCH * 8400 * 256;
    attnBase[1] = attnBase[0] + (long)BATCH * 6400 * 96;
    attnBase[2] = attnBase[1] + (long)BATCH * 1600 * 96;

    // ---- workspace layout (bytes) ----
    char* wsb = (char*)d_ws;
    float* nhwc[3];
    nhwc[0] = (float*)wsb;                                  // 26,214,400 B
    nhwc[1] = nhwc[0] + (long)BATCH * 6400 * 256;           //  6,553,600 B
    nhwc[2] = nhwc[1] + (long)BATCH * 1600 * 256;           //  1,638,400 B
    char* seg1 = wsb + 34406400;   // 26,214,400 B : dwconv y fp32 / tok1 fp32
    char* seg2 = seg1 + 26214400;  // 26,214,400 B : x_t fp32 / offsets fp32
    char* seg3 = seg2 + 26214400;  // 13,107,200 B : y_t bf16 / q_hi bf16 / h bf16
    char* seg4 = seg3 + 13107200;  // 13,107,200 B : q_lo bf16 / agg bf16
    char* seg5 = seg4 + 13107200;  // 26,214,400 B : FFN hidden bf16 (chunk 12800)
    char* segw = seg5 + 26214400;  // ~1.87 MB    : converted weights
    unsigned short* pwt  = (unsigned short*)segw;       // 3*65536
    unsigned short* opt  = pwt  + 3 * 65536;            // 65536
    unsigned short* ff1t = opt  + 65536;                // 262144
    unsigned short* ff2t = ff1t + 262144;               // 262144
    unsigned short* offh = ff2t + 262144;               // 49152
    unsigned short* offl = offh + 49152;                // 49152
    unsigned short* awh  = offl + 49152;                // 24576
    unsigned short* awl  = awh  + 24576;                // 24576

    float* ybuf  = (float*)seg1;
    float* tok1  = (float*)seg1;
    float* xt    = (float*)seg2;
    float* offs  = (float*)seg2;
    unsigned short* yt   = (unsigned short*)seg3;
    unsigned short* qhi  = (unsigned short*)seg3;
    unsigned short* hbf  = (unsigned short*)seg3;
    unsigned short* qlo  = (unsigned short*)seg4;
    unsigned short* aggb = (unsigned short*)seg4;
    unsigned short* hid  = (unsigned short*)seg5;

    // ---- weight conversion (tiny, every call; graph-safe) ----
    cvt_cast_kernel<<<(3 * 65536 + 255) / 256, 256, 0, stream>>>(pw_w, pwt, 3 * 65536);
    cvt_tr_kernel<<<(65536 + 255) / 256, 256, 0, stream>>>(op_w, opt, nullptr, 256, 256);
    cvt_tr_kernel<<<(262144 + 255) / 256, 256, 0, stream>>>(ff1_w, ff1t, nullptr, 256, 1024);
    cvt_tr_kernel<<<(262144 + 255) / 256, 256, 0, stream>>>(ff2_w, ff2t, nullptr, 1024, 256);
    cvt_tr_kernel<<<(49152 + 255) / 256, 256, 0, stream>>>(off_w, offh, offl, 256, 192);
    cvt_tr_kernel<<<(24576 + 255) / 256, 256, 0, stream>>>(aw_w, awh, awl, 256, 96);

    // ---------------- Stage A: local branch per level ----------------
    for (int l = 0; l < 3; ++l) {
        const int H = DIMS[l], Wd = DIMS[l], S = SS[l];
        const int total = BATCH * 256 * S;
        dwconv_kernel<<<(total + 255) / 256, 256, 0, stream>>>(
            feat[l], dw_w + (long)l * 256 * 9, dw_b + l * 256, ybuf, H, Wd, total);
        dim3 gt((S + 31) / 32, 8, BATCH);
        transpose_pack_kernel<<<gt, dim3(32, 8, 1), 0, stream>>>(ybuf, feat[l], yt, xt, S);
        // tokens[s,o] = gelu(y_t @ pw_w^T + pw_b) + x_t  -> nhwc[l] fp32
        const int M = BATCH * S;
        dim3 g(2, (M + 127) / 128);
        gemm_mfma<1, false, true, false, false><<<g, 256, 0, stream>>>(
            yt, nullptr, pwt + (long)l * 65536, nullptr, pw_b + l * 256,
            xt, 256, nhwc[l], M, 256, 256, 0, 0, 0, 0);
    }

    // ---------------- Stage B: per query level ----------------
    for (int l = 0; l < 3; ++l) {
        const int Wq = DIMS[l], Q = SS[l];
        const int M = BATCH * Q;
        float* attnP = outp + attnBase[l];

        // q = LN(tokens)+pos+lvl -> q_hi/q_lo bf16
        ln_kernel<1><<<M, 256, 0, stream>>>(nhwc[l], nq_g, nq_b, lvl_e + l * 256,
                                            qhi, qlo, Q, Wq);
        // offsets = tanh(q @ off_w + off_b) -> offs fp32 [M,192]   (split GEMM)
        {
            dim3 g(2, (M + 127) / 128);
            gemm_mfma<3, true, false, false, false><<<g, 256, 0, stream>>>(
                qhi, qlo, offh, offl, off_b, nullptr, 0,
                offs, M, 192, 256, 0, 0, 0, 0);
        }
        // attn logits -> attnP fp32 [M,96]   (split GEMM)
        {
            dim3 g(1, (M + 127) / 128);
            gemm_mfma<0, true, false, false, false><<<g, 256, 0, stream>>>(
                qhi, qlo, awh, awl, aw_b, nullptr, 0,
                attnP, M, 96, 256, 0, 0, 0, 0);
        }
        softmax12_kernel<<<(M * 8 + 255) / 256, 256, 0, stream>>>(attnP, M * 8);
        // deformable sampling -> agg bf16 [M,256]
        sample_kernel<<<M, 256, 0, stream>>>(offs, attnP, nhwc[0], nhwc[1], nhwc[2],
                                             aggb, Q, Wq, Wq);
        // tok1 = tokens + agg @ op_w + op_b
        {
            dim3 g(2, (M + 127) / 128);
            gemm_mfma<0, false, true, false, false><<<g, 256, 0, stream>>>(
                aggb, nullptr, opt, nullptr, op_b, nhwc[l], 256,
                tok1, M, 256, 256, 0, 0, 0, 0);
        }
        // h = LN(tok1) -> bf16
        ln_kernel<2><<<M, 256, 0, stream>>>(tok1, nf_g, nf_b, nullptr, hbf, nullptr, Q, Wq);
        // FFN in chunks of 12800 rows
        for (int c0 = 0; c0 < M; c0 += 12800) {
            int Mc = M - c0; if (Mc > 12800) Mc = 12800;
            dim3 g1(8, (Mc + 127) / 128);
            gemm_mfma<2, false, false, false, true><<<g1, 256, 0, stream>>>(
                hbf + (long)c0 * 256, nullptr, ff1t, nullptr, ff1_b, nullptr, 0,
                hid, Mc, 1024, 256, 0, 0, 0, 0);
            dim3 g2(2, (Mc + 127) / 128);
            gemm_mfma<0, false, true, true, false><<<g2, 256, 0, stream>>>(
                hid, nullptr, ff2t, nullptr, ff2_b, tok1 + (long)c0 * 256, 256,
                outp, Mc, 256, 1024, Q, 8400, tokOff[l], c0);
        }
    }
}

// Round 6
// 1074.118 us; speedup vs baseline: 2.4811x; 1.1132x over previous
//
#include <hip/hip_runtime.h>
#include <math.h>

#define BATCH 4
// D=256, HEADS=8, HD=32, L=3, P=4, FF=1024

typedef short bf16x8 __attribute__((ext_vector_type(8)));
typedef float f32x4 __attribute__((ext_vector_type(4)));

__device__ __forceinline__ unsigned short f2b(float x) {
    union { float f; unsigned u; } v; v.f = x;
    unsigned r = v.u + 0x7FFFu + ((v.u >> 16) & 1u);
    return (unsigned short)(r >> 16);
}
__device__ __forceinline__ float b2f(unsigned short b) {
    union { unsigned u; float f; } v; v.u = ((unsigned)b) << 16; return v.f;
}

// ---------------------------------------------------------------------------
// Weight conversion: cast fp32 -> bf16 (same layout)
__global__ __launch_bounds__(256)
void cvt_cast_kernel(const float* __restrict__ in, unsigned short* __restrict__ out, int n)
{
    int i = blockIdx.x * 256 + threadIdx.x;
    if (i < n) out[i] = f2b(in[i]);
}

// Weight conversion: transpose [R][C] -> [C][R] with optional hi/lo split
__global__ __launch_bounds__(256)
void cvt_tr_kernel(const float* __restrict__ in, unsigned short* __restrict__ hi,
                   unsigned short* __restrict__ lo, int R, int C)
{
    int i = blockIdx.x * 256 + threadIdx.x;
    if (i >= R * C) return;
    int r = i / C, c = i - r * C;
    float v = in[i];
    unsigned short h = f2b(v);
    hi[(long)c * R + r] = h;
    if (lo) lo[(long)c * R + r] = f2b(v - b2f(h));
}

// ---------------------------------------------------------------------------
// Depthwise 3x3 conv + bias (SAME). x: [B,256,H,W] fp32 -> y fp32 same layout.
__global__ __launch_bounds__(256)
void dwconv_kernel(const float* __restrict__ x, const float* __restrict__ wgt,
                   const float* __restrict__ bias, float* __restrict__ y,
                   int H, int W, int total)
{
    int idx = blockIdx.x * 256 + threadIdx.x;
    if (idx >= total) return;
    const int S = H * W;
    const int s = idx % S;
    const int bc = idx / S;
    const int c = bc & 255;
    const int i = s / W, j = s % W;
    const float* wp = wgt + c * 9;
    const float* xp = x + (long)bc * S;
    float acc = bias[c];
    #pragma unroll
    for (int dy = 0; dy < 3; ++dy) {
        const int ii = i + dy - 1;
        if (ii < 0 || ii >= H) continue;
        #pragma unroll
        for (int dx = 0; dx < 3; ++dx) {
            const int jj = j + dx - 1;
            if (jj < 0 || jj >= W) continue;
            acc = fmaf(xp[ii * W + jj], wp[dy * 3 + dx], acc);
        }
    }
    y[idx] = acc;
}

// ---------------------------------------------------------------------------
// Fused transpose: y NCHW fp32 -> y_t [B,S,256] bf16 ; x NCHW fp32 -> x_t fp32
__global__ __launch_bounds__(256)
void transpose_pack_kernel(const float* __restrict__ y, const float* __restrict__ x,
                           unsigned short* __restrict__ yt, float* __restrict__ xt, int S)
{
    __shared__ float ty[32][33];
    __shared__ float txs[32][33];
    const int b = blockIdx.z;
    const int s0 = blockIdx.x * 32, c0 = blockIdx.y * 32;
    const int tx = threadIdx.x, tyi = threadIdx.y;
    #pragma unroll
    for (int i = tyi; i < 32; i += 8) {
        const int s = s0 + tx;
        if (s < S) {
            ty[i][tx]  = y[((long)b * 256 + (c0 + i)) * S + s];
            txs[i][tx] = x[((long)b * 256 + (c0 + i)) * S + s];
        }
    }
    __syncthreads();
    #pragma unroll
    for (int i = tyi; i < 32; i += 8) {
        const int s = s0 + i;
        if (s < S) {
            const long o = ((long)b * S + s) * 256 + (c0 + tx);
            yt[o] = f2b(ty[tx][i]);
            xt[o] = txs[tx][i];
        }
    }
}

// ---------------------------------------------------------------------------
// MFMA bf16 GEMM: C[M,N] = epilogue(A[M,K] @ Wt[N,K]^T)
// A: [M][K] bf16 (hi, + lo if SPLIT); Wt: [N][K] bf16 (hi, + lo if SPLIT)
// Tile 128x128, BK=32, 4 waves each computing 64x64 via 4x4 frags of 16x16x32.
// LDS: linear rows, stride 80 B (32 elems used + pad) -> 16B-aligned b128 ops,
// 2-way bank aliasing only (free).
// ACT: 0 none, 1 gelu(exact), 2 relu, 3 tanh. RESID adds fp32 R[m*ldr+n].
// REMAP scatters C rows into concat layout. OUTBF16 writes bf16 else fp32.
#define LROW 80  // bytes per LDS row
template<int ACT, bool SPLIT, bool RESID, bool REMAP, bool OUTBF16>
__global__ __launch_bounds__(256)
void gemm_mfma(const unsigned short* __restrict__ Ah, const unsigned short* __restrict__ Al,
               const unsigned short* __restrict__ Wh, const unsigned short* __restrict__ Wl,
               const float* __restrict__ bias, const float* __restrict__ Rr, int ldr,
               void* __restrict__ Cout, int M, int N, int K,
               int outQ, int outTot, int outOff, int remapBase)
{
    __shared__ char AsH[128 * LROW];
    __shared__ char WsH[128 * LROW];
    __shared__ char AsL[SPLIT ? 128 * LROW : 16];
    __shared__ char WsL[SPLIT ? 128 * LROW : 16];

    const int t = threadIdx.x;
    const int m0 = blockIdx.y * 128, n0 = blockIdx.x * 128;
    // staging: 2 threads per row, 16 bf16 (32B) each
    const int srow = t >> 1;
    const int sby = (t & 1) * 32;           // byte offset within row
    const bool aok = (m0 + srow) < M;
    const bool wok = (n0 + srow) < N;
    const long arow = (long)(m0 + srow) * K;
    const long wrow = (long)(n0 + srow) * K;
    char* aW  = AsH + srow * LROW + sby;
    char* wW  = WsH + srow * LROW + sby;
    char* aW2 = AsL + (SPLIT ? srow * LROW + sby : 0);
    char* wW2 = WsL + (SPLIT ? srow * LROW + sby : 0);

    const int lane = t & 63;
    const int wv = t >> 6;
    const int wm = (wv >> 1) * 64, wn = (wv & 1) * 64;
    const int fr = lane & 15, fg = lane >> 4;
    const int fby = fg << 4;                 // 16B chunk per k-group

    f32x4 acc[4][4];
    #pragma unroll
    for (int i = 0; i < 4; ++i)
        #pragma unroll
        for (int j = 0; j < 4; ++j) acc[i][j] = (f32x4){0.f, 0.f, 0.f, 0.f};

    for (int k0 = 0; k0 < K; k0 += 32) {
        const int kk = k0 + ((t & 1) << 4);
        uint4 va0 = {}, va1 = {}, vw0 = {}, vw1 = {};
        uint4 ua0 = {}, ua1 = {}, uw0 = {}, uw1 = {};
        if (aok) {
            const uint4* p = (const uint4*)(Ah + arow + kk);
            va0 = p[0]; va1 = p[1];
            if (SPLIT) { const uint4* q = (const uint4*)(Al + arow + kk); ua0 = q[0]; ua1 = q[1]; }
        }
        if (wok) {
            const uint4* p = (const uint4*)(Wh + wrow + kk);
            vw0 = p[0]; vw1 = p[1];
            if (SPLIT) { const uint4* q = (const uint4*)(Wl + wrow + kk); uw0 = q[0]; uw1 = q[1]; }
        }
        __syncthreads();
        *(uint4*)(aW)      = va0; *(uint4*)(aW + 16) = va1;
        *(uint4*)(wW)      = vw0; *(uint4*)(wW + 16) = vw1;
        if (SPLIT) {
            *(uint4*)(aW2)      = ua0; *(uint4*)(aW2 + 16) = ua1;
            *(uint4*)(wW2)      = uw0; *(uint4*)(wW2 + 16) = uw1;
        }
        __syncthreads();
        bf16x8 af[4], bfr[4];
        #pragma unroll
        for (int i = 0; i < 4; ++i) {
            const int ra = wm + i * 16 + fr;
            af[i]  = *(const bf16x8*)(AsH + ra * LROW + fby);
            const int rb = wn + i * 16 + fr;
            bfr[i] = *(const bf16x8*)(WsH + rb * LROW + fby);
        }
        if (!SPLIT) {
            #pragma unroll
            for (int mi = 0; mi < 4; ++mi)
                #pragma unroll
                for (int ni = 0; ni < 4; ++ni)
                    acc[mi][ni] = __builtin_amdgcn_mfma_f32_16x16x32_bf16(af[mi], bfr[ni], acc[mi][ni], 0, 0, 0);
        } else {
            bf16x8 al[4], bl[4];
            #pragma unroll
            for (int i = 0; i < 4; ++i) {
                const int ra = wm + i * 16 + fr;
                al[i] = *(const bf16x8*)(AsL + ra * LROW + fby);
                const int rb = wn + i * 16 + fr;
                bl[i] = *(const bf16x8*)(WsL + rb * LROW + fby);
            }
            #pragma unroll
            for (int mi = 0; mi < 4; ++mi)
                #pragma unroll
                for (int ni = 0; ni < 4; ++ni) {
                    acc[mi][ni] = __builtin_amdgcn_mfma_f32_16x16x32_bf16(af[mi], bfr[ni], acc[mi][ni], 0, 0, 0);
                    acc[mi][ni] = __builtin_amdgcn_mfma_f32_16x16x32_bf16(af[mi], bl[ni],  acc[mi][ni], 0, 0, 0);
                    acc[mi][ni] = __builtin_amdgcn_mfma_f32_16x16x32_bf16(al[mi], bfr[ni], acc[mi][ni], 0, 0, 0);
                }
        }
    }

    float* Cf = (float*)Cout;
    unsigned short* Cb = (unsigned short*)Cout;
    #pragma unroll
    for (int mi = 0; mi < 4; ++mi) {
        #pragma unroll
        for (int ni = 0; ni < 4; ++ni) {
            #pragma unroll
            for (int j = 0; j < 4; ++j) {
                const int m = m0 + wm + mi * 16 + fg * 4 + j;
                const int n = n0 + wn + ni * 16 + fr;
                if (m < M && n < N) {
                    float v = acc[mi][ni][j] + bias[n];
                    if (ACT == 1) v = 0.5f * v * (1.f + erff(v * 0.70710678118654752f));
                    if (ACT == 2) v = fmaxf(v, 0.f);
                    if (ACT == 3) v = tanhf(v);
                    if (RESID) v += Rr[(long)m * ldr + n];
                    long crow = m;
                    if (REMAP) {
                        const int mg = m + remapBase;
                        const int bb = mg / outQ;
                        const int qi = mg - bb * outQ;
                        crow = (long)bb * outTot + outOff + qi;
                    }
                    if (OUTBF16) Cb[crow * (long)N + n] = f2b(v);
                    else         Cf[crow * (long)N + n] = v;
                }
            }
        }
    }
}

// ---------------------------------------------------------------------------
// LayerNorm over last dim (256), one token per 256-thread block.
// OUTMODE 1: +pos+lvl_emb, write bf16 hi (o1) and lo (o2) split.
// OUTMODE 2: plain LN, write single bf16 (o1).
template<int OUTMODE>
__global__ __launch_bounds__(256)
void ln_kernel(const float* __restrict__ x, const float* __restrict__ gamma,
               const float* __restrict__ beta, const float* __restrict__ lvlEmb,
               unsigned short* __restrict__ o1, unsigned short* __restrict__ o2,
               int Q, int Wq)
{
    const int m = blockIdx.x;
    const int c = threadIdx.x;
    const int qi = m % Q;
    const float v = x[(long)m * 256 + c];
    float s = v, s2 = v * v;
    #pragma unroll
    for (int o = 32; o > 0; o >>= 1) {
        s  += __shfl_down(s, o, 64);
        s2 += __shfl_down(s2, o, 64);
    }
    __shared__ float red[8];
    const int wid = c >> 6;
    if ((c & 63) == 0) { red[wid] = s; red[wid + 4] = s2; }
    __syncthreads();
    const float sum = red[0] + red[1] + red[2] + red[3];
    const float sq  = red[4] + red[5] + red[6] + red[7];
    const float mean = sum * (1.f / 256.f);
    const float var = sq * (1.f / 256.f) - mean * mean;
    const float rstd = 1.f / sqrtf(var + 1e-5f);
    float y = (v - mean) * rstd * gamma[c] + beta[c];
    if (OUTMODE == 1) {
        const int j = c & 63;
        const float denom = exp2f((float)j * (13.287712379549449f / 64.f)); // 10000^(j/64)
        const float coord = (c < 128) ? (float)(qi / Wq) : (float)(qi % Wq);
        const float ang = coord / denom;
        const float pv = ((c & 64) == 0) ? sinf(ang) : cosf(ang);
        y += pv + lvlEmb[c];
        const unsigned short h = f2b(y);
        o1[(long)m * 256 + c] = h;
        o2[(long)m * 256 + c] = f2b(y - b2f(h));
    } else {
        o1[(long)m * 256 + c] = f2b(y);
    }
}

// ---------------------------------------------------------------------------
// Softmax over groups of 12 (L*P), in place (fp32, lives in d_out attn region).
__global__ __launch_bounds__(256)
void softmax12_kernel(float* __restrict__ a, int total)
{
    const int t = blockIdx.x * 256 + threadIdx.x;
    if (t >= total) return;
    float* p = a + (long)t * 12;
    float v[12];
    float mx = -1e30f;
    #pragma unroll
    for (int k = 0; k < 12; ++k) { v[k] = p[k]; mx = fmaxf(mx, v[k]); }
    float sum = 0.f;
    #pragma unroll
    for (int k = 0; k < 12; ++k) { v[k] = expf(v[k] - mx); sum += v[k]; }
    const float inv = 1.f / sum;
    #pragma unroll
    for (int k = 0; k < 12; ++k) p[k] = v[k] * inv;
}

// ---------------------------------------------------------------------------
// Deformable-attention sampling, channel-vectorized x4.
// Block = 256 threads = 4 queries x 1 wave. Wave lane = h*8 + cg, thread owns
// 4 channels (float4 corner loads). Coordinate math redundancy drops 32->8
// lanes; load instruction count drops 4x. XCD-aware block swizzle for L2
// locality on the gather (nwg divisible by 8 at all levels).
__global__ __launch_bounds__(256)
void sample4_kernel(const float* __restrict__ off, const float* __restrict__ aw,
                    const float* __restrict__ f0, const float* __restrict__ f1,
                    const float* __restrict__ f2, unsigned short* __restrict__ agg,
                    int Q, int Wq, int Hq)
{
    const int nwg = gridDim.x;               // divisible by 8
    const int cpx = nwg >> 3;
    const int bid = blockIdx.x;
    const int swz = (bid & 7) * cpx + (bid >> 3);
    const int m0 = swz * 4;

    const int t = threadIdx.x;
    const int qloc = t >> 6;                 // 0..3
    const int lane = t & 63;
    const int h = lane >> 3;                 // head 0..7
    const int c4 = (lane & 7) << 2;          // channel-in-head 0,4,..,28
    const int m = m0 + qloc;
    const int qi = m % Q, b = m / Q;

    __shared__ float soff[4 * 192];
    __shared__ float saw[4 * 96];
    #pragma unroll
    for (int i = t; i < 4 * 192; i += 256) soff[i] = off[(long)m0 * 192 + i];
    #pragma unroll
    for (int i = t; i < 4 * 96; i += 256)  saw[i]  = aw[(long)m0 * 96 + i];
    __syncthreads();

    const float refx = 2.f * ((float)(qi % Wq) + 0.5f) / (float)Wq - 1.f;
    const float refy = 2.f * ((float)(qi / Wq) + 0.5f) / (float)Hq - 1.f;
    const float* fps[3] = {f0, f1, f2};
    const int DIMS[3] = {80, 40, 20};
    const float* po = soff + qloc * 192 + h * 24;
    const float* pa = saw + qloc * 96 + h * 12;

    float ax = 0.f, ay = 0.f, az = 0.f, aww = 0.f;
    #pragma unroll
    for (int lvl = 0; lvl < 3; ++lvl) {
        const int Ws = DIMS[lvl], Hs = DIMS[lvl];
        const float* fp = fps[lvl] + ((long)b * Hs * Ws) * 256 + (h * 32 + c4);
        #pragma unroll
        for (int p = 0; p < 4; ++p) {
            const float dx = po[lvl * 8 + p * 2 + 0];
            const float dy = po[lvl * 8 + p * 2 + 1];
            const float wa = pa[lvl * 4 + p];
            const float xx = (refx + dx + 1.f) * 0.5f * (float)(Ws - 1);
            const float yy = (refy + dy + 1.f) * 0.5f * (float)(Hs - 1);
            const float x0f = floorf(xx), y0f = floorf(yy);
            const float wx1 = xx - x0f, wy1 = yy - y0f;
            const float wx0 = 1.f - wx1, wy0 = 1.f - wy1;
            const int x0 = (int)x0f, y0 = (int)y0f;
            const bool vx0 = (x0 >= 0) && (x0 < Ws);
            const bool vx1 = (x0 + 1 >= 0) && (x0 + 1 < Ws);
            const bool vy0 = (y0 >= 0) && (y0 < Hs);
            const bool vy1 = (y0 + 1 >= 0) && (y0 + 1 < Hs);
            float vx_ = 0.f, vy_ = 0.f, vz_ = 0.f, vw_ = 0.f;
            if (vy0) {
                const long rb = (long)(y0 * Ws) * 256;
                const float w00 = wx0 * wy0, w10 = wx1 * wy0;
                if (vx0 && w00 != 0.f) {
                    const float4 c = *(const float4*)(fp + rb + (long)x0 * 256);
                    vx_ = fmaf(w00, c.x, vx_); vy_ = fmaf(w00, c.y, vy_);
                    vz_ = fmaf(w00, c.z, vz_); vw_ = fmaf(w00, c.w, vw_);
                }
                if (vx1 && w10 != 0.f) {
                    const float4 c = *(const float4*)(fp + rb + (long)(x0 + 1) * 256);
                    vx_ = fmaf(w10, c.x, vx_); vy_ = fmaf(w10, c.y, vy_);
                    vz_ = fmaf(w10, c.z, vz_); vw_ = fmaf(w10, c.w, vw_);
                }
            }
            if (vy1) {
                const long rb = (long)((y0 + 1) * Ws) * 256;
                const float w01 = wx0 * wy1, w11 = wx1 * wy1;
                if (vx0 && w01 != 0.f) {
                    const float4 c = *(const float4*)(fp + rb + (long)x0 * 256);
                    vx_ = fmaf(w01, c.x, vx_); vy_ = fmaf(w01, c.y, vy_);
                    vz_ = fmaf(w01, c.z, vz_); vw_ = fmaf(w01, c.w, vw_);
                }
                if (vx1 && w11 != 0.f) {
                    const float4 c = *(const float4*)(fp + rb + (long)(x0 + 1) * 256);
                    vx_ = fmaf(w11, c.x, vx_); vy_ = fmaf(w11, c.y, vy_);
                    vz_ = fmaf(w11, c.z, vz_); vw_ = fmaf(w11, c.w, vw_);
                }
            }
            ax = fmaf(wa, vx_, ax); ay = fmaf(wa, vy_, ay);
            az = fmaf(wa, vz_, az); aww = fmaf(wa, vw_, aww);
        }
    }
    ushort4 o;
    o.x = f2b(ax); o.y = f2b(ay); o.z = f2b(az); o.w = f2b(aww);
    *(ushort4*)&agg[(long)m * 256 + (h * 32 + c4)] = o;
}

// ---------------------------------------------------------------------------
extern "C" void kernel_launch(void* const* d_in, const int* in_sizes, int n_in,
                              void* d_out, int out_size, void* d_ws, size_t ws_size,
                              hipStream_t stream)
{
    (void)in_sizes; (void)n_in; (void)out_size; (void)ws_size;
    const float* feat[3] = {(const float*)d_in[0], (const float*)d_in[1], (const float*)d_in[2]};
    const float* dw_w  = (const float*)d_in[3];
    const float* dw_b  = (const float*)d_in[4];
    const float* pw_w  = (const float*)d_in[5];
    const float* pw_b  = (const float*)d_in[6];
    const float* off_w = (const float*)d_in[7];
    const float* off_b = (const float*)d_in[8];
    const float* aw_w  = (const float*)d_in[9];
    const float* aw_b  = (const float*)d_in[10];
    const float* op_w  = (const float*)d_in[11];
    const float* op_b  = (const float*)d_in[12];
    const float* nq_g  = (const float*)d_in[13];
    const float* nq_b  = (const float*)d_in[14];
    const float* nf_g  = (const float*)d_in[15];
    const float* nf_b  = (const float*)d_in[16];
    const float* ff1_w = (const float*)d_in[17];
    const float* ff1_b = (const float*)d_in[18];
    const float* ff2_w = (const float*)d_in[19];
    const float* ff2_b = (const float*)d_in[20];
    const float* lvl_e = (const float*)d_in[21];
    float* outp = (float*)d_out;

    const int DIMS[3]   = {80, 40, 20};
    const int SS[3]     = {6400, 1600, 400};
    const int tokOff[3] = {0, 6400, 8000};
    long attnBase[3];
    attnBase[0] = (long)BATCH * 8400 * 256;
    attnBase[1] = attnBase[0] + (long)BATCH * 6400 * 96;
    attnBase[2] = attnBase[1] + (long)BATCH * 1600 * 96;

    // ---- workspace layout (bytes) ----
    char* wsb = (char*)d_ws;
    float* nhwc[3];
    nhwc[0] = (float*)wsb;                                  // 26,214,400 B
    nhwc[1] = nhwc[0] + (long)BATCH * 6400 * 256;           //  6,553,600 B
    nhwc[2] = nhwc[1] + (long)BATCH * 1600 * 256;           //  1,638,400 B
    char* seg1 = wsb + 34406400;   // 26,214,400 B : dwconv y fp32 / tok1 fp32
    char* seg2 = seg1 + 26214400;  // 26,214,400 B : x_t fp32 / offsets fp32
    char* seg3 = seg2 + 26214400;  // 13,107,200 B : y_t bf16 / q_hi bf16 / h bf16
    char* seg4 = seg3 + 13107200;  // 13,107,200 B : q_lo bf16 / agg bf16
    char* seg5 = seg4 + 13107200;  // 26,214,400 B : FFN hidden bf16 (chunk 12800)
    char* segw = seg5 + 26214400;  // ~1.87 MB    : converted weights
    unsigned short* pwt  = (unsigned short*)segw;       // 3*65536
    unsigned short* opt  = pwt  + 3 * 65536;            // 65536
    unsigned short* ff1t = opt  + 65536;                // 262144
    unsigned short* ff2t = ff1t + 262144;               // 262144
    unsigned short* offh = ff2t + 262144;               // 49152
    unsigned short* offl = offh + 49152;                // 49152
    unsigned short* awh  = offl + 49152;                // 24576
    unsigned short* awl  = awh  + 24576;                // 24576

    float* ybuf  = (float*)seg1;
    float* tok1  = (float*)seg1;
    float* xt    = (float*)seg2;
    float* offs  = (float*)seg2;
    unsigned short* yt   = (unsigned short*)seg3;
    unsigned short* qhi  = (unsigned short*)seg3;
    unsigned short* hbf  = (unsigned short*)seg3;
    unsigned short* qlo  = (unsigned short*)seg4;
    unsigned short* aggb = (unsigned short*)seg4;
    unsigned short* hid  = (unsigned short*)seg5;

    // ---- weight conversion (tiny, every call; graph-safe) ----
    cvt_cast_kernel<<<(3 * 65536 + 255) / 256, 256, 0, stream>>>(pw_w, pwt, 3 * 65536);
    cvt_tr_kernel<<<(65536 + 255) / 256, 256, 0, stream>>>(op_w, opt, nullptr, 256, 256);
    cvt_tr_kernel<<<(262144 + 255) / 256, 256, 0, stream>>>(ff1_w, ff1t, nullptr, 256, 1024);
    cvt_tr_kernel<<<(262144 + 255) / 256, 256, 0, stream>>>(ff2_w, ff2t, nullptr, 1024, 256);
    cvt_tr_kernel<<<(49152 + 255) / 256, 256, 0, stream>>>(off_w, offh, offl, 256, 192);
    cvt_tr_kernel<<<(24576 + 255) / 256, 256, 0, stream>>>(aw_w, awh, awl, 256, 96);

    // ---------------- Stage A: local branch per level ----------------
    for (int l = 0; l < 3; ++l) {
        const int H = DIMS[l], Wd = DIMS[l], S = SS[l];
        const int total = BATCH * 256 * S;
        dwconv_kernel<<<(total + 255) / 256, 256, 0, stream>>>(
            feat[l], dw_w + (long)l * 256 * 9, dw_b + l * 256, ybuf, H, Wd, total);
        dim3 gt((S + 31) / 32, 8, BATCH);
        transpose_pack_kernel<<<gt, dim3(32, 8, 1), 0, stream>>>(ybuf, feat[l], yt, xt, S);
        // tokens[s,o] = gelu(y_t @ pw_w^T + pw_b) + x_t  -> nhwc[l] fp32
        const int M = BATCH * S;
        dim3 g(2, (M + 127) / 128);
        gemm_mfma<1, false, true, false, false><<<g, 256, 0, stream>>>(
            yt, nullptr, pwt + (long)l * 65536, nullptr, pw_b + l * 256,
            xt, 256, nhwc[l], M, 256, 256, 0, 0, 0, 0);
    }

    // ---------------- Stage B: per query level ----------------
    for (int l = 0; l < 3; ++l) {
        const int Wq = DIMS[l], Q = SS[l];
        const int M = BATCH * Q;
        float* attnP = outp + attnBase[l];

        // q = LN(tokens)+pos+lvl -> q_hi/q_lo bf16
        ln_kernel<1><<<M, 256, 0, stream>>>(nhwc[l], nq_g, nq_b, lvl_e + l * 256,
                                            qhi, qlo, Q, Wq);
        // offsets = tanh(q @ off_w + off_b) -> offs fp32 [M,192]   (split GEMM)
        {
            dim3 g(2, (M + 127) / 128);
            gemm_mfma<3, true, false, false, false><<<g, 256, 0, stream>>>(
                qhi, qlo, offh, offl, off_b, nullptr, 0,
                offs, M, 192, 256, 0, 0, 0, 0);
        }
        // attn logits -> attnP fp32 [M,96]   (split GEMM)
        {
            dim3 g(1, (M + 127) / 128);
            gemm_mfma<0, true, false, false, false><<<g, 256, 0, stream>>>(
                qhi, qlo, awh, awl, aw_b, nullptr, 0,
                attnP, M, 96, 256, 0, 0, 0, 0);
        }
        softmax12_kernel<<<(M * 8 + 255) / 256, 256, 0, stream>>>(attnP, M * 8);
        // deformable sampling -> agg bf16 [M,256]  (4 queries per block)
        sample4_kernel<<<M / 4, 256, 0, stream>>>(offs, attnP, nhwc[0], nhwc[1], nhwc[2],
                                                  aggb, Q, Wq, Wq);
        // tok1 = tokens + agg @ op_w + op_b
        {
            dim3 g(2, (M + 127) / 128);
            gemm_mfma<0, false, true, false, false><<<g, 256, 0, stream>>>(
                aggb, nullptr, opt, nullptr, op_b, nhwc[l], 256,
                tok1, M, 256, 256, 0, 0, 0, 0);
        }
        // h = LN(tok1) -> bf16
        ln_kernel<2><<<M, 256, 0, stream>>>(tok1, nf_g, nf_b, nullptr, hbf, nullptr, Q, Wq);
        // FFN in chunks of 12800 rows
        for (int c0 = 0; c0 < M; c0 += 12800) {
            int Mc = M - c0; if (Mc > 12800) Mc = 12800;
            dim3 g1(8, (Mc + 127) / 128);
            gemm_mfma<2, false, false, false, true><<<g1, 256, 0, stream>>>(
                hbf + (long)c0 * 256, nullptr, ff1t, nullptr, ff1_b, nullptr, 0,
                hid, Mc, 1024, 256, 0, 0, 0, 0);
            dim3 g2(2, (Mc + 127) / 128);
            gemm_mfma<0, false, true, true, false><<<g2, 256, 0, stream>>>(
                hid, nullptr, ff2t, nullptr, ff2_b, tok1 + (long)c0 * 256, 256,
                outp, Mc, 256, 1024, Q, 8400, tokOff[l], c0);
        }
    }
}

// Round 9
// 1012.307 us; speedup vs baseline: 2.6326x; 1.0611x over previous
//
#include <hip/hip_runtime.h>
#include <math.h>

#define BATCH 4
// D=256, HEADS=8, HD=32, L=3, P=4, FF=1024

typedef short bf16x8 __attribute__((ext_vector_type(8)));
typedef float f32x4 __attribute__((ext_vector_type(4)));

__device__ __forceinline__ unsigned short f2b(float x) {
    union { float f; unsigned u; } v; v.f = x;
    unsigned r = v.u + 0x7FFFu + ((v.u >> 16) & 1u);
    return (unsigned short)(r >> 16);
}
__device__ __forceinline__ float b2f(unsigned short b) {
    union { unsigned u; float f; } v; v.u = ((unsigned)b) << 16; return v.f;
}

// ---------------------------------------------------------------------------
// Weight conversion: cast fp32 -> bf16 (same layout)
__global__ __launch_bounds__(256)
void cvt_cast_kernel(const float* __restrict__ in, unsigned short* __restrict__ out, int n)
{
    int i = blockIdx.x * 256 + threadIdx.x;
    if (i < n) out[i] = f2b(in[i]);
}

// Weight conversion: transpose [R][C] -> [C][R] with optional hi/lo split
__global__ __launch_bounds__(256)
void cvt_tr_kernel(const float* __restrict__ in, unsigned short* __restrict__ hi,
                   unsigned short* __restrict__ lo, int R, int C)
{
    int i = blockIdx.x * 256 + threadIdx.x;
    if (i >= R * C) return;
    int r = i / C, c = i - r * C;
    float v = in[i];
    unsigned short h = f2b(v);
    hi[(long)c * R + r] = h;
    if (lo) lo[(long)c * R + r] = f2b(v - b2f(h));
}

// ---------------------------------------------------------------------------
// Depthwise 3x3 conv + bias (SAME). x: [B,256,H,W] fp32 -> y fp32 same layout.
__global__ __launch_bounds__(256)
void dwconv_kernel(const float* __restrict__ x, const float* __restrict__ wgt,
                   const float* __restrict__ bias, float* __restrict__ y,
                   int H, int W, int total)
{
    int idx = blockIdx.x * 256 + threadIdx.x;
    if (idx >= total) return;
    const int S = H * W;
    const int s = idx % S;
    const int bc = idx / S;
    const int c = bc & 255;
    const int i = s / W, j = s % W;
    const float* wp = wgt + c * 9;
    const float* xp = x + (long)bc * S;
    float acc = bias[c];
    #pragma unroll
    for (int dy = 0; dy < 3; ++dy) {
        const int ii = i + dy - 1;
        if (ii < 0 || ii >= H) continue;
        #pragma unroll
        for (int dx = 0; dx < 3; ++dx) {
            const int jj = j + dx - 1;
            if (jj < 0 || jj >= W) continue;
            acc = fmaf(xp[ii * W + jj], wp[dy * 3 + dx], acc);
        }
    }
    y[idx] = acc;
}

// ---------------------------------------------------------------------------
// Fused transpose: y NCHW fp32 -> y_t [B,S,256] bf16 ; x NCHW fp32 -> x_t fp32
__global__ __launch_bounds__(256)
void transpose_pack_kernel(const float* __restrict__ y, const float* __restrict__ x,
                           unsigned short* __restrict__ yt, float* __restrict__ xt, int S)
{
    __shared__ float ty[32][33];
    __shared__ float txs[32][33];
    const int b = blockIdx.z;
    const int s0 = blockIdx.x * 32, c0 = blockIdx.y * 32;
    const int tx = threadIdx.x, tyi = threadIdx.y;
    #pragma unroll
    for (int i = tyi; i < 32; i += 8) {
        const int s = s0 + tx;
        if (s < S) {
            ty[i][tx]  = y[((long)b * 256 + (c0 + i)) * S + s];
            txs[i][tx] = x[((long)b * 256 + (c0 + i)) * S + s];
        }
    }
    __syncthreads();
    #pragma unroll
    for (int i = tyi; i < 32; i += 8) {
        const int s = s0 + i;
        if (s < S) {
            const long o = ((long)b * S + s) * 256 + (c0 + tx);
            yt[o] = f2b(ty[tx][i]);
            xt[o] = txs[tx][i];
        }
    }
}

// ---------------------------------------------------------------------------
// OLD (verified R3) reg-staged MFMA GEMM, kept ONLY for the hi/lo-split
// offsets projection. LDS rows stride 80 B.
#define LROW 80
template<int ACT, bool SPLIT, bool RESID, bool REMAP, bool OUTBF16>
__global__ __launch_bounds__(256)
void gemm_mfma(const unsigned short* __restrict__ Ah, const unsigned short* __restrict__ Al,
               const unsigned short* __restrict__ Wh, const unsigned short* __restrict__ Wl,
               const float* __restrict__ bias, const float* __restrict__ Rr, int ldr,
               void* __restrict__ Cout, int M, int N, int K,
               int outQ, int outTot, int outOff, int remapBase)
{
    __shared__ char AsH[128 * LROW];
    __shared__ char WsH[128 * LROW];
    __shared__ char AsL[SPLIT ? 128 * LROW : 16];
    __shared__ char WsL[SPLIT ? 128 * LROW : 16];

    const int t = threadIdx.x;
    const int m0 = blockIdx.y * 128, n0 = blockIdx.x * 128;
    const int srow = t >> 1;
    const int sby = (t & 1) * 32;
    const bool aok = (m0 + srow) < M;
    const bool wok = (n0 + srow) < N;
    const long arow = (long)(m0 + srow) * K;
    const long wrow = (long)(n0 + srow) * K;
    char* aW  = AsH + srow * LROW + sby;
    char* wW  = WsH + srow * LROW + sby;
    char* aW2 = AsL + (SPLIT ? srow * LROW + sby : 0);
    char* wW2 = WsL + (SPLIT ? srow * LROW + sby : 0);

    const int lane = t & 63;
    const int wv = t >> 6;
    const int wm = (wv >> 1) * 64, wn = (wv & 1) * 64;
    const int fr = lane & 15, fg = lane >> 4;
    const int fby = fg << 4;

    f32x4 acc[4][4];
    #pragma unroll
    for (int i = 0; i < 4; ++i)
        #pragma unroll
        for (int j = 0; j < 4; ++j) acc[i][j] = (f32x4){0.f, 0.f, 0.f, 0.f};

    for (int k0 = 0; k0 < K; k0 += 32) {
        const int kk = k0 + ((t & 1) << 4);
        uint4 va0 = {}, va1 = {}, vw0 = {}, vw1 = {};
        uint4 ua0 = {}, ua1 = {}, uw0 = {}, uw1 = {};
        if (aok) {
            const uint4* p = (const uint4*)(Ah + arow + kk);
            va0 = p[0]; va1 = p[1];
            if (SPLIT) { const uint4* q = (const uint4*)(Al + arow + kk); ua0 = q[0]; ua1 = q[1]; }
        }
        if (wok) {
            const uint4* p = (const uint4*)(Wh + wrow + kk);
            vw0 = p[0]; vw1 = p[1];
            if (SPLIT) { const uint4* q = (const uint4*)(Wl + wrow + kk); uw0 = q[0]; uw1 = q[1]; }
        }
        __syncthreads();
        *(uint4*)(aW)      = va0; *(uint4*)(aW + 16) = va1;
        *(uint4*)(wW)      = vw0; *(uint4*)(wW + 16) = vw1;
        if (SPLIT) {
            *(uint4*)(aW2)      = ua0; *(uint4*)(aW2 + 16) = ua1;
            *(uint4*)(wW2)      = uw0; *(uint4*)(wW2 + 16) = uw1;
        }
        __syncthreads();
        bf16x8 af[4], bfr[4];
        #pragma unroll
        for (int i = 0; i < 4; ++i) {
            const int ra = wm + i * 16 + fr;
            af[i]  = *(const bf16x8*)(AsH + ra * LROW + fby);
            const int rb = wn + i * 16 + fr;
            bfr[i] = *(const bf16x8*)(WsH + rb * LROW + fby);
        }
        if (!SPLIT) {
            #pragma unroll
            for (int mi = 0; mi < 4; ++mi)
                #pragma unroll
                for (int ni = 0; ni < 4; ++ni)
                    acc[mi][ni] = __builtin_amdgcn_mfma_f32_16x16x32_bf16(af[mi], bfr[ni], acc[mi][ni], 0, 0, 0);
        } else {
            bf16x8 al[4], bl[4];
            #pragma unroll
            for (int i = 0; i < 4; ++i) {
                const int ra = wm + i * 16 + fr;
                al[i] = *(const bf16x8*)(AsL + ra * LROW + fby);
                const int rb = wn + i * 16 + fr;
                bl[i] = *(const bf16x8*)(WsL + rb * LROW + fby);
            }
            #pragma unroll
            for (int mi = 0; mi < 4; ++mi)
                #pragma unroll
                for (int ni = 0; ni < 4; ++ni) {
                    acc[mi][ni] = __builtin_amdgcn_mfma_f32_16x16x32_bf16(af[mi], bfr[ni], acc[mi][ni], 0, 0, 0);
                    acc[mi][ni] = __builtin_amdgcn_mfma_f32_16x16x32_bf16(af[mi], bl[ni],  acc[mi][ni], 0, 0, 0);
                    acc[mi][ni] = __builtin_amdgcn_mfma_f32_16x16x32_bf16(al[mi], bfr[ni], acc[mi][ni], 0, 0, 0);
                }
        }
    }

    float* Cf = (float*)Cout;
    unsigned short* Cb = (unsigned short*)Cout;
    #pragma unroll
    for (int mi = 0; mi < 4; ++mi) {
        #pragma unroll
        for (int ni = 0; ni < 4; ++ni) {
            #pragma unroll
            for (int j = 0; j < 4; ++j) {
                const int m = m0 + wm + mi * 16 + fg * 4 + j;
                const int n = n0 + wn + ni * 16 + fr;
                if (m < M && n < N) {
                    float v = acc[mi][ni][j] + bias[n];
                    if (ACT == 1) v = 0.5f * v * (1.f + erff(v * 0.70710678118654752f));
                    if (ACT == 2) v = fmaxf(v, 0.f);
                    if (ACT == 3) v = tanhf(v);
                    if (RESID) v += Rr[(long)m * ldr + n];
                    long crow = m;
                    if (REMAP) {
                        const int mg = m + remapBase;
                        const int bb = mg / outQ;
                        const int qi = mg - bb * outQ;
                        crow = (long)bb * outTot + outOff + qi;
                    }
                    if (OUTBF16) Cb[crow * (long)N + n] = f2b(v);
                    else         Cf[crow * (long)N + n] = v;
                }
            }
        }
    }
}

// ---------------------------------------------------------------------------
// NEW pipelined MFMA GEMM (non-split): global_load_lds(16B) staging, linear
// 64B LDS rows double-buffered, source-side XOR swizzle chunk^=((row>>1)&3)
// (involution, applied on both stage-source and ds_read -> rule #21) giving
// exactly-even bank coverage for ds_read_b128. Per K-step:
//   stage(next) -> s_waitcnt vmcnt(4) -> s_barrier -> ds_read+MFMA -> s_barrier
// so the 4 staging loads stay in flight across a full iteration (T3/T4 min).
// REQUIREMENTS: M % 128 == 0 (all call sites satisfy); N<128 tiles over-read
// W rows (must be allocated memory; columns masked in epilogue).
template<int ACT, bool RESID, bool REMAP, bool OUTBF16>
__global__ __launch_bounds__(256)
void gemm_mfma2(const unsigned short* __restrict__ Ah,
                const unsigned short* __restrict__ Wh,
                const float* __restrict__ bias, const float* __restrict__ Rr, int ldr,
                void* __restrict__ Cout, int M, int N, int K,
                int outQ, int outTot, int outOff, int remapBase)
{
    __shared__ __attribute__((aligned(16))) char As[2][8192];
    __shared__ __attribute__((aligned(16))) char Ws[2][8192];

    const int t = threadIdx.x;
    const int lane = t & 63;
    const int wv = t >> 6;
    const int m0 = blockIdx.y * 128, n0 = blockIdx.x * 128;
    const unsigned short* Abase = Ah + (long)m0 * K;
    const unsigned short* Wbase = Wh + (long)n0 * K;

    // per-wave staging: 2 segments of 16 rows each for A and W (4 vmem ops)
    const int seg0 = wv * 2;
    const int rl0 = seg0 * 16 + (lane >> 2);
    const int rl1 = rl0 + 16;
    const int g0 = (lane & 3) ^ ((rl0 >> 1) & 3);
    const int g1 = (lane & 3) ^ ((rl1 >> 1) & 3);
    const long ao0 = (long)rl0 * K + g0 * 8;
    const long ao1 = (long)rl1 * K + g1 * 8;

    const int wm = (wv >> 1) * 64, wn = (wv & 1) * 64;
    const int fr = lane & 15, fg = lane >> 4;

    f32x4 acc[4][4];
    #pragma unroll
    for (int i = 0; i < 4; ++i)
        #pragma unroll
        for (int j = 0; j < 4; ++j) acc[i][j] = (f32x4){0.f, 0.f, 0.f, 0.f};

    const int NT = K >> 5;

#define STAGE(BUF, K0)                                                                          \
    do {                                                                                        \
        __builtin_amdgcn_global_load_lds(                                                       \
            (const __attribute__((address_space(1))) void*)(Abase + ao0 + (K0)),                \
            (__attribute__((address_space(3))) void*)(&As[BUF][seg0 * 1024]), 16, 0, 0);        \
        __builtin_amdgcn_global_load_lds(                                                       \
            (const __attribute__((address_space(1))) void*)(Wbase + ao0 + (K0)),                \
            (__attribute__((address_space(3))) void*)(&Ws[BUF][seg0 * 1024]), 16, 0, 0);        \
        __builtin_amdgcn_global_load_lds(                                                       \
            (const __attribute__((address_space(1))) void*)(Abase + ao1 + (K0)),                \
            (__attribute__((address_space(3))) void*)(&As[BUF][seg0 * 1024 + 1024]), 16, 0, 0); \
        __builtin_amdgcn_global_load_lds(                                                       \
            (const __attribute__((address_space(1))) void*)(Wbase + ao1 + (K0)),                \
            (__attribute__((address_space(3))) void*)(&Ws[BUF][seg0 * 1024 + 1024]), 16, 0, 0); \
    } while (0)

    STAGE(0, 0);
    int cur = 0;
    for (int tt = 0; tt < NT; ++tt) {
        if (tt + 1 < NT) {
            STAGE(cur ^ 1, (tt + 1) << 5);
            asm volatile("s_waitcnt vmcnt(4)" ::: "memory");
        } else {
            asm volatile("s_waitcnt vmcnt(0)" ::: "memory");
        }
        __builtin_amdgcn_s_barrier();
        bf16x8 af[4], bfr[4];
        #pragma unroll
        for (int i = 0; i < 4; ++i) {
            const int ra = wm + i * 16 + fr;
            af[i]  = *(const bf16x8*)(&As[cur][ra * 64 + ((fg ^ ((ra >> 1) & 3)) << 4)]);
            const int rb = wn + i * 16 + fr;
            bfr[i] = *(const bf16x8*)(&Ws[cur][rb * 64 + ((fg ^ ((rb >> 1) & 3)) << 4)]);
        }
        #pragma unroll
        for (int mi = 0; mi < 4; ++mi)
            #pragma unroll
            for (int ni = 0; ni < 4; ++ni)
                acc[mi][ni] = __builtin_amdgcn_mfma_f32_16x16x32_bf16(af[mi], bfr[ni], acc[mi][ni], 0, 0, 0);
        __builtin_amdgcn_s_barrier();
        cur ^= 1;
    }
#undef STAGE

    float* Cf = (float*)Cout;
    unsigned short* Cb = (unsigned short*)Cout;
    #pragma unroll
    for (int mi = 0; mi < 4; ++mi) {
        #pragma unroll
        for (int ni = 0; ni < 4; ++ni) {
            #pragma unroll
            for (int j = 0; j < 4; ++j) {
                const int m = m0 + wm + mi * 16 + fg * 4 + j;
                const int n = n0 + wn + ni * 16 + fr;
                if (m < M && n < N) {
                    float v = acc[mi][ni][j] + bias[n];
                    if (ACT == 1) v = 0.5f * v * (1.f + erff(v * 0.70710678118654752f));
                    if (ACT == 2) v = fmaxf(v, 0.f);
                    if (ACT == 3) v = tanhf(v);
                    if (RESID) v += Rr[(long)m * ldr + n];
                    long crow = m;
                    if (REMAP) {
                        const int mg = m + remapBase;
                        const int bb = mg / outQ;
                        const int qi = mg - bb * outQ;
                        crow = (long)bb * outTot + outOff + qi;
                    }
                    if (OUTBF16) Cb[crow * (long)N + n] = f2b(v);
                    else         Cf[crow * (long)N + n] = v;
                }
            }
        }
    }
}

// ---------------------------------------------------------------------------
// LayerNorm over last dim (256), one token per 256-thread block.
template<int OUTMODE>
__global__ __launch_bounds__(256)
void ln_kernel(const float* __restrict__ x, const float* __restrict__ gamma,
               const float* __restrict__ beta, const float* __restrict__ lvlEmb,
               unsigned short* __restrict__ o1, unsigned short* __restrict__ o2,
               int Q, int Wq)
{
    const int m = blockIdx.x;
    const int c = threadIdx.x;
    const int qi = m % Q;
    const float v = x[(long)m * 256 + c];
    float s = v, s2 = v * v;
    #pragma unroll
    for (int o = 32; o > 0; o >>= 1) {
        s  += __shfl_down(s, o, 64);
        s2 += __shfl_down(s2, o, 64);
    }
    __shared__ float red[8];
    const int wid = c >> 6;
    if ((c & 63) == 0) { red[wid] = s; red[wid + 4] = s2; }
    __syncthreads();
    const float sum = red[0] + red[1] + red[2] + red[3];
    const float sq  = red[4] + red[5] + red[6] + red[7];
    const float mean = sum * (1.f / 256.f);
    const float var = sq * (1.f / 256.f) - mean * mean;
    const float rstd = 1.f / sqrtf(var + 1e-5f);
    float y = (v - mean) * rstd * gamma[c] + beta[c];
    if (OUTMODE == 1) {
        const int j = c & 63;
        const float denom = exp2f((float)j * (13.287712379549449f / 64.f)); // 10000^(j/64)
        const float coord = (c < 128) ? (float)(qi / Wq) : (float)(qi % Wq);
        const float ang = coord / denom;
        const float pv = ((c & 64) == 0) ? sinf(ang) : cosf(ang);
        y += pv + lvlEmb[c];
        const unsigned short h = f2b(y);
        o1[(long)m * 256 + c] = h;
        o2[(long)m * 256 + c] = f2b(y - b2f(h));
    } else {
        o1[(long)m * 256 + c] = f2b(y);
    }
}

// ---------------------------------------------------------------------------
__global__ __launch_bounds__(256)
void softmax12_kernel(float* __restrict__ a, int total)
{
    const int t = blockIdx.x * 256 + threadIdx.x;
    if (t >= total) return;
    float* p = a + (long)t * 12;
    float v[12];
    float mx = -1e30f;
    #pragma unroll
    for (int k = 0; k < 12; ++k) { v[k] = p[k]; mx = fmaxf(mx, v[k]); }
    float sum = 0.f;
    #pragma unroll
    for (int k = 0; k < 12; ++k) { v[k] = expf(v[k] - mx); sum += v[k]; }
    const float inv = 1.f / sum;
    #pragma unroll
    for (int k = 0; k < 12; ++k) p[k] = v[k] * inv;
}

// ---------------------------------------------------------------------------
// Deformable-attention sampling, channel-vectorized x4 (unchanged from R6).
__global__ __launch_bounds__(256)
void sample4_kernel(const float* __restrict__ off, const float* __restrict__ aw,
                    const float* __restrict__ f0, const float* __restrict__ f1,
                    const float* __restrict__ f2, unsigned short* __restrict__ agg,
                    int Q, int Wq, int Hq)
{
    const int nwg = gridDim.x;
    const int cpx = nwg >> 3;
    const int bid = blockIdx.x;
    const int swz = (bid & 7) * cpx + (bid >> 3);
    const int m0 = swz * 4;

    const int t = threadIdx.x;
    const int qloc = t >> 6;
    const int lane = t & 63;
    const int h = lane >> 3;
    const int c4 = (lane & 7) << 2;
    const int m = m0 + qloc;
    const int qi = m % Q, b = m / Q;

    __shared__ float soff[4 * 192];
    __shared__ float saw[4 * 96];
    #pragma unroll
    for (int i = t; i < 4 * 192; i += 256) soff[i] = off[(long)m0 * 192 + i];
    #pragma unroll
    for (int i = t; i < 4 * 96; i += 256)  saw[i]  = aw[(long)m0 * 96 + i];
    __syncthreads();

    const float refx = 2.f * ((float)(qi % Wq) + 0.5f) / (float)Wq - 1.f;
    const float refy = 2.f * ((float)(qi / Wq) + 0.5f) / (float)Hq - 1.f;
    const float* fps[3] = {f0, f1, f2};
    const int DIMS[3] = {80, 40, 20};
    const float* po = soff + qloc * 192 + h * 24;
    const float* pa = saw + qloc * 96 + h * 12;

    float ax = 0.f, ay = 0.f, az = 0.f, aww = 0.f;
    #pragma unroll
    for (int lvl = 0; lvl < 3; ++lvl) {
        const int Ws = DIMS[lvl], Hs = DIMS[lvl];
        const float* fp = fps[lvl] + ((long)b * Hs * Ws) * 256 + (h * 32 + c4);
        #pragma unroll
        for (int p = 0; p < 4; ++p) {
            const float dx = po[lvl * 8 + p * 2 + 0];
            const float dy = po[lvl * 8 + p * 2 + 1];
            const float wa = pa[lvl * 4 + p];
            const float xx = (refx + dx + 1.f) * 0.5f * (float)(Ws - 1);
            const float yy = (refy + dy + 1.f) * 0.5f * (float)(Hs - 1);
            const float x0f = floorf(xx), y0f = floorf(yy);
            const float wx1 = xx - x0f, wy1 = yy - y0f;
            const float wx0 = 1.f - wx1, wy0 = 1.f - wy1;
            const int x0 = (int)x0f, y0 = (int)y0f;
            const bool vx0 = (x0 >= 0) && (x0 < Ws);
            const bool vx1 = (x0 + 1 >= 0) && (x0 + 1 < Ws);
            const bool vy0 = (y0 >= 0) && (y0 < Hs);
            const bool vy1 = (y0 + 1 >= 0) && (y0 + 1 < Hs);
            float vx_ = 0.f, vy_ = 0.f, vz_ = 0.f, vw_ = 0.f;
            if (vy0) {
                const long rb = (long)(y0 * Ws) * 256;
                const float w00 = wx0 * wy0, w10 = wx1 * wy0;
                if (vx0 && w00 != 0.f) {
                    const float4 c = *(const float4*)(fp + rb + (long)x0 * 256);
                    vx_ = fmaf(w00, c.x, vx_); vy_ = fmaf(w00, c.y, vy_);
                    vz_ = fmaf(w00, c.z, vz_); vw_ = fmaf(w00, c.w, vw_);
                }
                if (vx1 && w10 != 0.f) {
                    const float4 c = *(const float4*)(fp + rb + (long)(x0 + 1) * 256);
                    vx_ = fmaf(w10, c.x, vx_); vy_ = fmaf(w10, c.y, vy_);
                    vz_ = fmaf(w10, c.z, vz_); vw_ = fmaf(w10, c.w, vw_);
                }
            }
            if (vy1) {
                const long rb = (long)((y0 + 1) * Ws) * 256;
                const float w01 = wx0 * wy1, w11 = wx1 * wy1;
                if (vx0 && w01 != 0.f) {
                    const float4 c = *(const float4*)(fp + rb + (long)x0 * 256);
                    vx_ = fmaf(w01, c.x, vx_); vy_ = fmaf(w01, c.y, vy_);
                    vz_ = fmaf(w01, c.z, vz_); vw_ = fmaf(w01, c.w, vw_);
                }
                if (vx1 && w11 != 0.f) {
                    const float4 c = *(const float4*)(fp + rb + (long)(x0 + 1) * 256);
                    vx_ = fmaf(w11, c.x, vx_); vy_ = fmaf(w11, c.y, vy_);
                    vz_ = fmaf(w11, c.z, vz_); vw_ = fmaf(w11, c.w, vw_);
                }
            }
            ax = fmaf(wa, vx_, ax); ay = fmaf(wa, vy_, ay);
            az = fmaf(wa, vz_, az); aww = fmaf(wa, vw_, aww);
        }
    }
    ushort4 o;
    o.x = f2b(ax); o.y = f2b(ay); o.z = f2b(az); o.w = f2b(aww);
    *(ushort4*)&agg[(long)m * 256 + (h * 32 + c4)] = o;
}

// ---------------------------------------------------------------------------
extern "C" void kernel_launch(void* const* d_in, const int* in_sizes, int n_in,
                              void* d_out, int out_size, void* d_ws, size_t ws_size,
                              hipStream_t stream)
{
    (void)in_sizes; (void)n_in; (void)out_size; (void)ws_size;
    const float* feat[3] = {(const float*)d_in[0], (const float*)d_in[1], (const float*)d_in[2]};
    const float* dw_w  = (const float*)d_in[3];
    const float* dw_b  = (const float*)d_in[4];
    const float* pw_w  = (const float*)d_in[5];
    const float* pw_b  = (const float*)d_in[6];
    const float* off_w = (const float*)d_in[7];
    const float* off_b = (const float*)d_in[8];
    const float* aw_w  = (const float*)d_in[9];
    const float* aw_b  = (const float*)d_in[10];
    const float* op_w  = (const float*)d_in[11];
    const float* op_b  = (const float*)d_in[12];
    const float* nq_g  = (const float*)d_in[13];
    const float* nq_b  = (const float*)d_in[14];
    const float* nf_g  = (const float*)d_in[15];
    const float* nf_b  = (const float*)d_in[16];
    const float* ff1_w = (const float*)d_in[17];
    const float* ff1_b = (const float*)d_in[18];
    const float* ff2_w = (const float*)d_in[19];
    const float* ff2_b = (const float*)d_in[20];
    const float* lvl_e = (const float*)d_in[21];
    float* outp = (float*)d_out;

    const int DIMS[3]   = {80, 40, 20};
    const int SS[3]     = {6400, 1600, 400};
    const int tokOff[3] = {0, 6400, 8000};
    long attnBase[3];
    attnBase[0] = (long)BATCH * 8400 * 256;
    attnBase[1] = attnBase[0] + (long)BATCH * 6400 * 96;
    attnBase[2] = attnBase[1] + (long)BATCH * 1600 * 96;

    // ---- workspace layout (bytes) ----
    char* wsb = (char*)d_ws;
    float* nhwc[3];
    nhwc[0] = (float*)wsb;                                  // 26,214,400 B
    nhwc[1] = nhwc[0] + (long)BATCH * 6400 * 256;           //  6,553,600 B
    nhwc[2] = nhwc[1] + (long)BATCH * 1600 * 256;           //  1,638,400 B
    char* seg1 = wsb + 34406400;   // 26,214,400 B : dwconv y fp32 / tok1 fp32
    char* seg2 = seg1 + 26214400;  // 26,214,400 B : x_t fp32 / offsets fp32
    char* seg3 = seg2 + 26214400;  // 13,107,200 B : y_t bf16 / q_hi bf16 / h bf16
    char* seg4 = seg3 + 13107200;  // 13,107,200 B : q_lo bf16 / agg bf16
    char* seg5 = seg4 + 13107200;  // 26,214,400 B : FFN hidden bf16 (chunk 12800)
    char* segw = seg5 + 26214400;  // ~1.87 MB    : converted weights
    // Order: small (possibly over-read) buffers FIRST so N<128 tile
    // over-reads land in allocated weight memory (gemm_mfma2 requirement).
    unsigned short* offh = (unsigned short*)segw;       // 49152
    unsigned short* offl = offh + 49152;                // 49152
    unsigned short* awh  = offl + 49152;                // 24576
    unsigned short* awl  = awh  + 24576;                // 24576
    unsigned short* pwt  = awl  + 24576;                // 3*65536
    unsigned short* opt  = pwt  + 3 * 65536;            // 65536
    unsigned short* ff1t = opt  + 65536;                // 262144
    unsigned short* ff2t = ff1t + 262144;               // 262144

    float* ybuf  = (float*)seg1;
    float* tok1  = (float*)seg1;
    float* xt    = (float*)seg2;
    float* offs  = (float*)seg2;
    unsigned short* yt   = (unsigned short*)seg3;
    unsigned short* qhi  = (unsigned short*)seg3;
    unsigned short* hbf  = (unsigned short*)seg3;
    unsigned short* qlo  = (unsigned short*)seg4;
    unsigned short* aggb = (unsigned short*)seg4;
    unsigned short* hid  = (unsigned short*)seg5;

    // ---- weight conversion (tiny, every call; graph-safe) ----
    cvt_cast_kernel<<<(3 * 65536 + 255) / 256, 256, 0, stream>>>(pw_w, pwt, 3 * 65536);
    cvt_tr_kernel<<<(65536 + 255) / 256, 256, 0, stream>>>(op_w, opt, nullptr, 256, 256);
    cvt_tr_kernel<<<(262144 + 255) / 256, 256, 0, stream>>>(ff1_w, ff1t, nullptr, 256, 1024);
    cvt_tr_kernel<<<(262144 + 255) / 256, 256, 0, stream>>>(ff2_w, ff2t, nullptr, 1024, 256);
    cvt_tr_kernel<<<(49152 + 255) / 256, 256, 0, stream>>>(off_w, offh, offl, 256, 192);
    cvt_tr_kernel<<<(24576 + 255) / 256, 256, 0, stream>>>(aw_w, awh, awl, 256, 96);

    // ---------------- Stage A: local branch per level ----------------
    for (int l = 0; l < 3; ++l) {
        const int H = DIMS[l], Wd = DIMS[l], S = SS[l];
        const int total = BATCH * 256 * S;
        dwconv_kernel<<<(total + 255) / 256, 256, 0, stream>>>(
            feat[l], dw_w + (long)l * 256 * 9, dw_b + l * 256, ybuf, H, Wd, total);
        dim3 gt((S + 31) / 32, 8, BATCH);
        transpose_pack_kernel<<<gt, dim3(32, 8, 1), 0, stream>>>(ybuf, feat[l], yt, xt, S);
        // tokens[s,o] = gelu(y_t @ pw_w^T + pw_b) + x_t  -> nhwc[l] fp32
        const int M = BATCH * S;
        dim3 g(2, (M + 127) / 128);
        gemm_mfma2<1, true, false, false><<<g, 256, 0, stream>>>(
            yt, pwt + (long)l * 65536, pw_b + l * 256,
            xt, 256, nhwc[l], M, 256, 256, 0, 0, 0, 0);
    }

    // ---------------- Stage B: per query level ----------------
    for (int l = 0; l < 3; ++l) {
        const int Wq = DIMS[l], Q = SS[l];
        const int M = BATCH * Q;
        float* attnP = outp + attnBase[l];

        // q = LN(tokens)+pos+lvl -> q_hi/q_lo bf16
        ln_kernel<1><<<M, 256, 0, stream>>>(nhwc[l], nq_g, nq_b, lvl_e + l * 256,
                                            qhi, qlo, Q, Wq);
        // offsets = tanh(q @ off_w + off_b) -> offs fp32 [M,192]  (split, old kernel)
        {
            dim3 g(2, (M + 127) / 128);
            gemm_mfma<3, true, false, false, false><<<g, 256, 0, stream>>>(
                qhi, qlo, offh, offl, off_b, nullptr, 0,
                offs, M, 192, 256, 0, 0, 0, 0);
        }
        // attn logits -> attnP fp32 [M,96]  (plain bf16, new kernel)
        {
            dim3 g(1, (M + 127) / 128);
            gemm_mfma2<0, false, false, false><<<g, 256, 0, stream>>>(
                qhi, awh, aw_b, nullptr, 0,
                attnP, M, 96, 256, 0, 0, 0, 0);
        }
        softmax12_kernel<<<(M * 8 + 255) / 256, 256, 0, stream>>>(attnP, M * 8);
        // deformable sampling -> agg bf16 [M,256]  (4 queries per block)
        sample4_kernel<<<M / 4, 256, 0, stream>>>(offs, attnP, nhwc[0], nhwc[1], nhwc[2],
                                                  aggb, Q, Wq, Wq);
        // tok1 = tokens + agg @ op_w + op_b
        {
            dim3 g(2, (M + 127) / 128);
            gemm_mfma2<0, true, false, false><<<g, 256, 0, stream>>>(
                aggb, opt, op_b, nhwc[l], 256,
                tok1, M, 256, 256, 0, 0, 0, 0);
        }
        // h = LN(tok1) -> bf16
        ln_kernel<2><<<M, 256, 0, stream>>>(tok1, nf_g, nf_b, nullptr, hbf, nullptr, Q, Wq);
        // FFN in chunks of 12800 rows
        for (int c0 = 0; c0 < M; c0 += 12800) {
            int Mc = M - c0; if (Mc > 12800) Mc = 12800;
            dim3 g1(8, (Mc + 127) / 128);
            gemm_mfma2<2, false, false, true><<<g1, 256, 0, stream>>>(
                hbf + (long)c0 * 256, ff1t, ff1_b, nullptr, 0,
                hid, Mc, 1024, 256, 0, 0, 0, 0);
            dim3 g2(2, (Mc + 127) / 128);
            gemm_mfma2<0, true, true, false><<<g2, 256, 0, stream>>>(
                hid, ff2t, ff2_b, tok1 + (long)c0 * 256, 256,
                outp, Mc, 256, 1024, Q, 8400, tokOff[l], c0);
        }
    }
}

// Round 10
// 723.003 us; speedup vs baseline: 3.6861x; 1.4001x over previous
//
#include <hip/hip_runtime.h>
#include <math.h>

#define BATCH 4
// D=256, HEADS=8, HD=32, L=3, P=4, FF=1024
// Fused row layout: r in [0,33600) level-major, batch-within-level:
//   l0: [0,25600)=b*6400+qi  l1: [25600,32000)=25600+b*1600+qi  l2: [32000,33600)

typedef short bf16x8 __attribute__((ext_vector_type(8)));
typedef float f32x4 __attribute__((ext_vector_type(4)));

__device__ __forceinline__ unsigned short f2b(float x) {
    union { float f; unsigned u; } v; v.f = x;
    unsigned r = v.u + 0x7FFFu + ((v.u >> 16) & 1u);
    return (unsigned short)(r >> 16);
}
__device__ __forceinline__ float b2f(unsigned short b) {
    union { unsigned u; float f; } v; v.u = ((unsigned)b) << 16; return v.f;
}

// ---------------------------------------------------------------------------
// All weight conversions in ONE kernel (ranges over 860160 threads).
__global__ __launch_bounds__(256)
void cvt_all_kernel(const float* __restrict__ pw_w, const float* __restrict__ op_w,
                    const float* __restrict__ ff1_w, const float* __restrict__ ff2_w,
                    const float* __restrict__ off_w, const float* __restrict__ aw_w,
                    unsigned short* __restrict__ pwt, unsigned short* __restrict__ opt,
                    unsigned short* __restrict__ ff1t, unsigned short* __restrict__ ff2t,
                    unsigned short* __restrict__ offh, unsigned short* __restrict__ offl,
                    unsigned short* __restrict__ awh, unsigned short* __restrict__ awl)
{
    int i = blockIdx.x * 256 + threadIdx.x;
    if (i < 196608) { pwt[i] = f2b(pw_w[i]); return; }
    i -= 196608;
    if (i < 65536) { int r = i >> 8, c = i & 255; opt[(long)c * 256 + r] = f2b(op_w[i]); return; }
    i -= 65536;
    if (i < 262144) { int r = i >> 10, c = i & 1023; ff1t[(long)c * 256 + r] = f2b(ff1_w[i]); return; }
    i -= 262144;
    if (i < 262144) { int r = i >> 8, c = i & 255; ff2t[(long)c * 1024 + r] = f2b(ff2_w[i]); return; }
    i -= 262144;
    if (i < 49152) {
        int r = i / 192, c = i - r * 192;
        float v = off_w[i]; unsigned short h = f2b(v);
        offh[(long)c * 256 + r] = h; offl[(long)c * 256 + r] = f2b(v - b2f(h)); return;
    }
    i -= 49152;
    if (i < 24576) {
        int r = i / 96, c = i - r * 96;
        float v = aw_w[i]; unsigned short h = f2b(v);
        awh[(long)c * 256 + r] = h; awl[(long)c * 256 + r] = f2b(v - b2f(h)); return;
    }
}

// ---------------------------------------------------------------------------
// Fused depthwise 3x3 conv, all 3 levels in one dispatch (8,601,600 threads).
__global__ __launch_bounds__(256)
void dwconv_all_kernel(const float* __restrict__ f0, const float* __restrict__ f1,
                       const float* __restrict__ f2, const float* __restrict__ wgt,
                       const float* __restrict__ bias, float* __restrict__ y)
{
    const int idx = blockIdx.x * 256 + threadIdx.x;
    int l, W; long lbase; const float* x;
    if (idx < 6553600)      { l = 0; lbase = 0;       W = 80; x = f0; }
    else if (idx < 8192000) { l = 1; lbase = 6553600; W = 40; x = f1; }
    else                    { l = 2; lbase = 8192000; W = 20; x = f2; }
    const int local = idx - (int)lbase;
    const int S = W * W;
    const int s = local % S;
    const int bc = local / S;
    const int c = bc & 255;
    const int i = s / W, j = s % W;
    const float* wp = wgt + l * 2304 + c * 9;
    const float* xp = x + (long)bc * S;
    float acc = bias[l * 256 + c];
    #pragma unroll
    for (int dy = 0; dy < 3; ++dy) {
        const int ii = i + dy - 1;
        if (ii < 0 || ii >= W) continue;
        #pragma unroll
        for (int dx = 0; dx < 3; ++dx) {
            const int jj = j + dx - 1;
            if (jj < 0 || jj >= W) continue;
            acc = fmaf(xp[ii * W + jj], wp[dy * 3 + dx], acc);
        }
    }
    y[idx] = acc;
}

// ---------------------------------------------------------------------------
// Fused transpose: y NCHW fp32 -> y_t [rows,256] bf16 ; x NCHW fp32 -> x_t fp32
__global__ __launch_bounds__(256)
void transpose_pack_kernel(const float* __restrict__ y, const float* __restrict__ x,
                           unsigned short* __restrict__ yt, float* __restrict__ xt, int S)
{
    __shared__ float ty[32][33];
    __shared__ float txs[32][33];
    const int b = blockIdx.z;
    const int s0 = blockIdx.x * 32, c0 = blockIdx.y * 32;
    const int tx = threadIdx.x, tyi = threadIdx.y;
    #pragma unroll
    for (int i = tyi; i < 32; i += 8) {
        const int s = s0 + tx;
        if (s < S) {
            ty[i][tx]  = y[((long)b * 256 + (c0 + i)) * S + s];
            txs[i][tx] = x[((long)b * 256 + (c0 + i)) * S + s];
        }
    }
    __syncthreads();
    #pragma unroll
    for (int i = tyi; i < 32; i += 8) {
        const int s = s0 + i;
        if (s < S) {
            const long o = ((long)b * S + s) * 256 + (c0 + tx);
            yt[o] = f2b(ty[tx][i]);
            xt[o] = txs[tx][i];
        }
    }
}

// ---------------------------------------------------------------------------
// OLD (verified R3) reg-staged MFMA GEMM, kept ONLY for the hi/lo-split
// offsets projection (guarded A/W, no REMAP).
#define LROW 80
template<int ACT>
__global__ __launch_bounds__(256)
void gemm_split(const unsigned short* __restrict__ Ah, const unsigned short* __restrict__ Al,
                const unsigned short* __restrict__ Wh, const unsigned short* __restrict__ Wl,
                const float* __restrict__ bias, float* __restrict__ Cf,
                int M, int N, int K)
{
    __shared__ char AsH[128 * LROW];
    __shared__ char WsH[128 * LROW];
    __shared__ char AsL[128 * LROW];
    __shared__ char WsL[128 * LROW];

    const int t = threadIdx.x;
    const int m0 = blockIdx.y * 128, n0 = blockIdx.x * 128;
    const int srow = t >> 1;
    const int sby = (t & 1) * 32;
    const bool aok = (m0 + srow) < M;
    const bool wok = (n0 + srow) < N;
    const long arow = (long)(m0 + srow) * K;
    const long wrow = (long)(n0 + srow) * K;
    char* aW  = AsH + srow * LROW + sby;
    char* wW  = WsH + srow * LROW + sby;
    char* aW2 = AsL + srow * LROW + sby;
    char* wW2 = WsL + srow * LROW + sby;

    const int lane = t & 63;
    const int wv = t >> 6;
    const int wm = (wv >> 1) * 64, wn = (wv & 1) * 64;
    const int fr = lane & 15, fg = lane >> 4;
    const int fby = fg << 4;

    f32x4 acc[4][4];
    #pragma unroll
    for (int i = 0; i < 4; ++i)
        #pragma unroll
        for (int j = 0; j < 4; ++j) acc[i][j] = (f32x4){0.f, 0.f, 0.f, 0.f};

    for (int k0 = 0; k0 < K; k0 += 32) {
        const int kk = k0 + ((t & 1) << 4);
        uint4 va0 = {}, va1 = {}, vw0 = {}, vw1 = {};
        uint4 ua0 = {}, ua1 = {}, uw0 = {}, uw1 = {};
        if (aok) {
            const uint4* p = (const uint4*)(Ah + arow + kk);
            va0 = p[0]; va1 = p[1];
            const uint4* q = (const uint4*)(Al + arow + kk); ua0 = q[0]; ua1 = q[1];
        }
        if (wok) {
            const uint4* p = (const uint4*)(Wh + wrow + kk);
            vw0 = p[0]; vw1 = p[1];
            const uint4* q = (const uint4*)(Wl + wrow + kk); uw0 = q[0]; uw1 = q[1];
        }
        __syncthreads();
        *(uint4*)(aW)      = va0; *(uint4*)(aW + 16) = va1;
        *(uint4*)(wW)      = vw0; *(uint4*)(wW + 16) = vw1;
        *(uint4*)(aW2)      = ua0; *(uint4*)(aW2 + 16) = ua1;
        *(uint4*)(wW2)      = uw0; *(uint4*)(wW2 + 16) = uw1;
        __syncthreads();
        bf16x8 af[4], bfr[4], al[4], bl[4];
        #pragma unroll
        for (int i = 0; i < 4; ++i) {
            const int ra = wm + i * 16 + fr;
            af[i] = *(const bf16x8*)(AsH + ra * LROW + fby);
            al[i] = *(const bf16x8*)(AsL + ra * LROW + fby);
            const int rb = wn + i * 16 + fr;
            bfr[i] = *(const bf16x8*)(WsH + rb * LROW + fby);
            bl[i]  = *(const bf16x8*)(WsL + rb * LROW + fby);
        }
        #pragma unroll
        for (int mi = 0; mi < 4; ++mi)
            #pragma unroll
            for (int ni = 0; ni < 4; ++ni) {
                acc[mi][ni] = __builtin_amdgcn_mfma_f32_16x16x32_bf16(af[mi], bfr[ni], acc[mi][ni], 0, 0, 0);
                acc[mi][ni] = __builtin_amdgcn_mfma_f32_16x16x32_bf16(af[mi], bl[ni],  acc[mi][ni], 0, 0, 0);
                acc[mi][ni] = __builtin_amdgcn_mfma_f32_16x16x32_bf16(al[mi], bfr[ni], acc[mi][ni], 0, 0, 0);
            }
    }

    #pragma unroll
    for (int mi = 0; mi < 4; ++mi)
        #pragma unroll
        for (int ni = 0; ni < 4; ++ni)
            #pragma unroll
            for (int j = 0; j < 4; ++j) {
                const int m = m0 + wm + mi * 16 + fg * 4 + j;
                const int n = n0 + wn + ni * 16 + fr;
                if (m < M && n < N) {
                    float v = acc[mi][ni][j] + bias[n];
                    if (ACT == 3) v = tanhf(v);
                    Cf[(long)m * N + n] = v;
                }
            }
}

// ---------------------------------------------------------------------------
// Pipelined MFMA GEMM (verified R9): global_load_lds(16B), double-buffered,
// both-sides XOR swizzle, vmcnt(4) held across iteration.
// LVLSEL: per-128-tile weight/bias select for the fused pointwise conv
//         (boundaries 25600/32000 are multiples of 128).
// REMAP: hardcoded 3-range concat remap for the final output write.
// REQUIREMENTS: grid covers ceil(M/128) tiles; A buffer must be allocated
// through row (tiles*128-1); N<128 tiles over-read W rows (allocated mem).
template<int ACT, bool RESID, bool REMAP, bool OUTBF16, bool LVLSEL>
__global__ __launch_bounds__(256)
void gemm_mfma2(const unsigned short* __restrict__ Ah,
                const unsigned short* __restrict__ Wh,
                const float* __restrict__ bias, const float* __restrict__ Rr, int ldr,
                void* __restrict__ Cout, int M, int N, int K, int remapBase)
{
    __shared__ __attribute__((aligned(16))) char As[2][8192];
    __shared__ __attribute__((aligned(16))) char Ws[2][8192];

    const int t = threadIdx.x;
    const int lane = t & 63;
    const int wv = t >> 6;
    const int m0 = blockIdx.y * 128, n0 = blockIdx.x * 128;
    if (LVLSEL) {
        const int l = (m0 < 25600) ? 0 : (m0 < 32000 ? 1 : 2);
        Wh += (long)l * 65536; bias += l * 256;
    }
    const unsigned short* Abase = Ah + (long)m0 * K;
    const unsigned short* Wbase = Wh + (long)n0 * K;

    const int seg0 = wv * 2;
    const int rl0 = seg0 * 16 + (lane >> 2);
    const int rl1 = rl0 + 16;
    const int g0 = (lane & 3) ^ ((rl0 >> 1) & 3);
    const int g1 = (lane & 3) ^ ((rl1 >> 1) & 3);
    const long ao0 = (long)rl0 * K + g0 * 8;
    const long ao1 = (long)rl1 * K + g1 * 8;

    const int wm = (wv >> 1) * 64, wn = (wv & 1) * 64;
    const int fr = lane & 15, fg = lane >> 4;

    f32x4 acc[4][4];
    #pragma unroll
    for (int i = 0; i < 4; ++i)
        #pragma unroll
        for (int j = 0; j < 4; ++j) acc[i][j] = (f32x4){0.f, 0.f, 0.f, 0.f};

    const int NT = K >> 5;

#define STAGE(BUF, K0)                                                                          \
    do {                                                                                        \
        __builtin_amdgcn_global_load_lds(                                                       \
            (const __attribute__((address_space(1))) void*)(Abase + ao0 + (K0)),                \
            (__attribute__((address_space(3))) void*)(&As[BUF][seg0 * 1024]), 16, 0, 0);        \
        __builtin_amdgcn_global_load_lds(                                                       \
            (const __attribute__((address_space(1))) void*)(Wbase + ao0 + (K0)),                \
            (__attribute__((address_space(3))) void*)(&Ws[BUF][seg0 * 1024]), 16, 0, 0);        \
        __builtin_amdgcn_global_load_lds(                                                       \
            (const __attribute__((address_space(1))) void*)(Abase + ao1 + (K0)),                \
            (__attribute__((address_space(3))) void*)(&As[BUF][seg0 * 1024 + 1024]), 16, 0, 0); \
        __builtin_amdgcn_global_load_lds(                                                       \
            (const __attribute__((address_space(1))) void*)(Wbase + ao1 + (K0)),                \
            (__attribute__((address_space(3))) void*)(&Ws[BUF][seg0 * 1024 + 1024]), 16, 0, 0); \
    } while (0)

    STAGE(0, 0);
    int cur = 0;
    for (int tt = 0; tt < NT; ++tt) {
        if (tt + 1 < NT) {
            STAGE(cur ^ 1, (tt + 1) << 5);
            asm volatile("s_waitcnt vmcnt(4)" ::: "memory");
        } else {
            asm volatile("s_waitcnt vmcnt(0)" ::: "memory");
        }
        __builtin_amdgcn_s_barrier();
        bf16x8 af[4], bfr[4];
        #pragma unroll
        for (int i = 0; i < 4; ++i) {
            const int ra = wm + i * 16 + fr;
            af[i]  = *(const bf16x8*)(&As[cur][ra * 64 + ((fg ^ ((ra >> 1) & 3)) << 4)]);
            const int rb = wn + i * 16 + fr;
            bfr[i] = *(const bf16x8*)(&Ws[cur][rb * 64 + ((fg ^ ((rb >> 1) & 3)) << 4)]);
        }
        #pragma unroll
        for (int mi = 0; mi < 4; ++mi)
            #pragma unroll
            for (int ni = 0; ni < 4; ++ni)
                acc[mi][ni] = __builtin_amdgcn_mfma_f32_16x16x32_bf16(af[mi], bfr[ni], acc[mi][ni], 0, 0, 0);
        __builtin_amdgcn_s_barrier();
        cur ^= 1;
    }
#undef STAGE

    float* Cf = (float*)Cout;
    unsigned short* Cb = (unsigned short*)Cout;
    #pragma unroll
    for (int mi = 0; mi < 4; ++mi) {
        #pragma unroll
        for (int ni = 0; ni < 4; ++ni) {
            #pragma unroll
            for (int j = 0; j < 4; ++j) {
                const int m = m0 + wm + mi * 16 + fg * 4 + j;
                const int n = n0 + wn + ni * 16 + fr;
                if (m < M && n < N) {
                    float v = acc[mi][ni][j] + bias[n];
                    if (ACT == 1) v = 0.5f * v * (1.f + erff(v * 0.70710678118654752f));
                    if (ACT == 2) v = fmaxf(v, 0.f);
                    if (ACT == 3) v = tanhf(v);
                    if (RESID) v += Rr[(long)m * ldr + n];
                    long crow = m;
                    if (REMAP) {
                        const int rg = m + remapBase;
                        int Q, toff, base;
                        if (rg < 25600)      { Q = 6400; toff = 0;    base = 0; }
                        else if (rg < 32000) { Q = 1600; toff = 6400; base = 25600; }
                        else                 { Q = 400;  toff = 8000; base = 32000; }
                        const int local = rg - base;
                        const int bb = local / Q;
                        const int qi = local - bb * Q;
                        crow = (long)bb * 8400 + toff + qi;
                    }
                    if (OUTBF16) Cb[crow * (long)N + n] = f2b(v);
                    else         Cf[crow * (long)N + n] = v;
                }
            }
        }
    }
}

// ---------------------------------------------------------------------------
// Fused LayerNorm over last dim (256), one token per block, grid = 33600.
// OUTMODE 1: +pos+lvl_emb (per-row level lookup), bf16 hi/lo split out.
// OUTMODE 2: plain LN -> single bf16.
template<int OUTMODE>
__global__ __launch_bounds__(256)
void ln_all_kernel(const float* __restrict__ x, const float* __restrict__ gamma,
                   const float* __restrict__ beta, const float* __restrict__ lvlEmbAll,
                   unsigned short* __restrict__ o1, unsigned short* __restrict__ o2)
{
    const int m = blockIdx.x;
    const int c = threadIdx.x;
    const float v = x[(long)m * 256 + c];
    float s = v, s2 = v * v;
    #pragma unroll
    for (int o = 32; o > 0; o >>= 1) {
        s  += __shfl_down(s, o, 64);
        s2 += __shfl_down(s2, o, 64);
    }
    __shared__ float red[8];
    const int wid = c >> 6;
    if ((c & 63) == 0) { red[wid] = s; red[wid + 4] = s2; }
    __syncthreads();
    const float sum = red[0] + red[1] + red[2] + red[3];
    const float sq  = red[4] + red[5] + red[6] + red[7];
    const float mean = sum * (1.f / 256.f);
    const float var = sq * (1.f / 256.f) - mean * mean;
    const float rstd = 1.f / sqrtf(var + 1e-5f);
    float y = (v - mean) * rstd * gamma[c] + beta[c];
    if (OUTMODE == 1) {
        int qi, Wq, lidx;
        if (m < 25600)      { const int loc = m;         const int b_ = loc / 6400; qi = loc - b_ * 6400; Wq = 80; lidx = 0; }
        else if (m < 32000) { const int loc = m - 25600; const int b_ = loc / 1600; qi = loc - b_ * 1600; Wq = 40; lidx = 1; }
        else                { const int loc = m - 32000; const int b_ = loc / 400;  qi = loc - b_ * 400;  Wq = 20; lidx = 2; }
        const int j = c & 63;
        const float denom = exp2f((float)j * (13.287712379549449f / 64.f)); // 10000^(j/64)
        const float coord = (c < 128) ? (float)(qi / Wq) : (float)(qi % Wq);
        const float ang = coord / denom;
        const float pv = ((c & 64) == 0) ? sinf(ang) : cosf(ang);
        y += pv + lvlEmbAll[lidx * 256 + c];
        const unsigned short h = f2b(y);
        o1[(long)m * 256 + c] = h;
        o2[(long)m * 256 + c] = f2b(y - b2f(h));
    } else {
        o1[(long)m * 256 + c] = f2b(y);
    }
}

// ---------------------------------------------------------------------------
__global__ __launch_bounds__(256)
void softmax12_kernel(float* __restrict__ a, int total)
{
    const int t = blockIdx.x * 256 + threadIdx.x;
    if (t >= total) return;
    float* p = a + (long)t * 12;
    float v[12];
    float mx = -1e30f;
    #pragma unroll
    for (int k = 0; k < 12; ++k) { v[k] = p[k]; mx = fmaxf(mx, v[k]); }
    float sum = 0.f;
    #pragma unroll
    for (int k = 0; k < 12; ++k) { v[k] = expf(v[k] - mx); sum += v[k]; }
    const float inv = 1.f / sum;
    #pragma unroll
    for (int k = 0; k < 12; ++k) p[k] = v[k] * inv;
}

// ---------------------------------------------------------------------------
// Fused deformable sampling, all levels, grid = 8400 blocks (4 queries each).
// Level boundaries (block 6400, 8000) never straddle a block. XCD swizzle.
__global__ __launch_bounds__(256)
void sample4_all_kernel(const float* __restrict__ off, const float* __restrict__ aw,
                        const float* __restrict__ f0, const float* __restrict__ f1,
                        const float* __restrict__ f2, unsigned short* __restrict__ agg)
{
    const int nwg = gridDim.x;               // 8400, divisible by 8
    const int cpx = nwg >> 3;
    const int bid = blockIdx.x;
    const int swz = (bid & 7) * cpx + (bid >> 3);
    const int m0 = swz * 4;

    const int t = threadIdx.x;
    const int qloc = t >> 6;
    const int lane = t & 63;
    const int h = lane >> 3;
    const int c4 = (lane & 7) << 2;
    const int m = m0 + qloc;

    int b, qi, Wq;
    if (m0 < 25600)      { const int loc = m;         b = loc / 6400; qi = loc - b * 6400; Wq = 80; }
    else if (m0 < 32000) { const int loc = m - 25600; b = loc / 1600; qi = loc - b * 1600; Wq = 40; }
    else                 { const int loc = m - 32000; b = loc / 400;  qi = loc - b * 400;  Wq = 20; }

    __shared__ float soff[4 * 192];
    __shared__ float saw[4 * 96];
    #pragma unroll
    for (int i = t; i < 4 * 192; i += 256) soff[i] = off[(long)m0 * 192 + i];
    #pragma unroll
    for (int i = t; i < 4 * 96; i += 256)  saw[i]  = aw[(long)m0 * 96 + i];
    __syncthreads();

    const float refx = 2.f * ((float)(qi % Wq) + 0.5f) / (float)Wq - 1.f;
    const float refy = 2.f * ((float)(qi / Wq) + 0.5f) / (float)Wq - 1.f;
    const float* fps[3] = {f0, f1, f2};
    const int DIMS[3] = {80, 40, 20};
    const float* po = soff + qloc * 192 + h * 24;
    const float* pa = saw + qloc * 96 + h * 12;

    float ax = 0.f, ay = 0.f, az = 0.f, aww = 0.f;
    #pragma unroll
    for (int lvl = 0; lvl < 3; ++lvl) {
        const int Ws = DIMS[lvl], Hs = DIMS[lvl];
        const float* fp = fps[lvl] + ((long)b * Hs * Ws) * 256 + (h * 32 + c4);
        #pragma unroll
        for (int p = 0; p < 4; ++p) {
            const float dx = po[lvl * 8 + p * 2 + 0];
            const float dy = po[lvl * 8 + p * 2 + 1];
            const float wa = pa[lvl * 4 + p];
            const float xx = (refx + dx + 1.f) * 0.5f * (float)(Ws - 1);
            const float yy = (refy + dy + 1.f) * 0.5f * (float)(Hs - 1);
            const float x0f = floorf(xx), y0f = floorf(yy);
            const float wx1 = xx - x0f, wy1 = yy - y0f;
            const float wx0 = 1.f - wx1, wy0 = 1.f - wy1;
            const int x0 = (int)x0f, y0 = (int)y0f;
            const bool vx0 = (x0 >= 0) && (x0 < Ws);
            const bool vx1 = (x0 + 1 >= 0) && (x0 + 1 < Ws);
            const bool vy0 = (y0 >= 0) && (y0 < Hs);
            const bool vy1 = (y0 + 1 >= 0) && (y0 + 1 < Hs);
            float vx_ = 0.f, vy_ = 0.f, vz_ = 0.f, vw_ = 0.f;
            if (vy0) {
                const long rb = (long)(y0 * Ws) * 256;
                const float w00 = wx0 * wy0, w10 = wx1 * wy0;
                if (vx0 && w00 != 0.f) {
                    const float4 cc = *(const float4*)(fp + rb + (long)x0 * 256);
                    vx_ = fmaf(w00, cc.x, vx_); vy_ = fmaf(w00, cc.y, vy_);
                    vz_ = fmaf(w00, cc.z, vz_); vw_ = fmaf(w00, cc.w, vw_);
                }
                if (vx1 && w10 != 0.f) {
                    const float4 cc = *(const float4*)(fp + rb + (long)(x0 + 1) * 256);
                    vx_ = fmaf(w10, cc.x, vx_); vy_ = fmaf(w10, cc.y, vy_);
                    vz_ = fmaf(w10, cc.z, vz_); vw_ = fmaf(w10, cc.w, vw_);
                }
            }
            if (vy1) {
                const long rb = (long)((y0 + 1) * Ws) * 256;
                const float w01 = wx0 * wy1, w11 = wx1 * wy1;
                if (vx0 && w01 != 0.f) {
                    const float4 cc = *(const float4*)(fp + rb + (long)x0 * 256);
                    vx_ = fmaf(w01, cc.x, vx_); vy_ = fmaf(w01, cc.y, vy_);
                    vz_ = fmaf(w01, cc.z, vz_); vw_ = fmaf(w01, cc.w, vw_);
                }
                if (vx1 && w11 != 0.f) {
                    const float4 cc = *(const float4*)(fp + rb + (long)(x0 + 1) * 256);
                    vx_ = fmaf(w11, cc.x, vx_); vy_ = fmaf(w11, cc.y, vy_);
                    vz_ = fmaf(w11, cc.z, vz_); vw_ = fmaf(w11, cc.w, vw_);
                }
            }
            ax = fmaf(wa, vx_, ax); ay = fmaf(wa, vy_, ay);
            az = fmaf(wa, vz_, az); aww = fmaf(wa, vw_, aww);
        }
    }
    ushort4 o;
    o.x = f2b(ax); o.y = f2b(ay); o.z = f2b(az); o.w = f2b(aww);
    *(ushort4*)&agg[(long)m * 256 + (h * 32 + c4)] = o;
}

// ---------------------------------------------------------------------------
extern "C" void kernel_launch(void* const* d_in, const int* in_sizes, int n_in,
                              void* d_out, int out_size, void* d_ws, size_t ws_size,
                              hipStream_t stream)
{
    (void)in_sizes; (void)n_in; (void)out_size; (void)ws_size;
    const float* feat[3] = {(const float*)d_in[0], (const float*)d_in[1], (const float*)d_in[2]};
    const float* dw_w  = (const float*)d_in[3];
    const float* dw_b  = (const float*)d_in[4];
    const float* pw_w  = (const float*)d_in[5];
    const float* pw_b  = (const float*)d_in[6];
    const float* off_w = (const float*)d_in[7];
    const float* off_b = (const float*)d_in[8];
    const float* aw_w  = (const float*)d_in[9];
    const float* aw_b  = (const float*)d_in[10];
    const float* op_w  = (const float*)d_in[11];
    const float* op_b  = (const float*)d_in[12];
    const float* nq_g  = (const float*)d_in[13];
    const float* nq_b  = (const float*)d_in[14];
    const float* nf_g  = (const float*)d_in[15];
    const float* nf_b  = (const float*)d_in[16];
    const float* ff1_b = (const float*)d_in[18];
    const float* ff2_b = (const float*)d_in[20];
    const float* ff1_w = (const float*)d_in[17];
    const float* ff2_w = (const float*)d_in[19];
    const float* lvl_e = (const float*)d_in[21];
    float* outp = (float*)d_out;

    const int DIMS[3] = {80, 40, 20};
    const int SS[3]   = {6400, 1600, 400};
    const int rowBase[3] = {0, 25600, 32000};      // fused row offsets
    const long nchwOff[3] = {0, 6553600, 8192000}; // fused NCHW float offsets
    const long attn0 = (long)BATCH * 8400 * 256;   // attn region base (contiguous 33600x96)

    // ---- workspace layout (bytes); total ~139.6 MB ----
    char* wsb = (char*)d_ws;
    float* tokens = (float*)wsb;                       // 34,406,400 : fused nhwc tokens [33600,256] f32
    char* seg1 = wsb + 34406400;   // 34,406,400 : ybuf (fused NCHW dwconv out) / tok1 [33600,256] f32
    char* seg2 = seg1 + 34406400;  // 34,406,400 : xt f32 / offs f32 / hid bf16 (time-shared)
    char* seg3 = seg2 + 34406400;  // 17,235,968 : yt bf16 / qhi bf16 / hbf bf16 (33664 rows pad)
    char* seg4 = seg3 + 17235968;  // 17,235,968 : qlo bf16 / aggb bf16
    char* segw = seg4 + 17235968;  // 1,867,776 : converted weights
    // small (over-readable) W buffers first, mid-segment => row over-reads allocated
    unsigned short* offh = (unsigned short*)segw;       // 49152
    unsigned short* offl = offh + 49152;                // 49152
    unsigned short* awh  = offl + 49152;                // 24576
    unsigned short* awl  = awh  + 24576;                // 24576
    unsigned short* pwt  = awl  + 24576;                // 3*65536
    unsigned short* opt  = pwt  + 3 * 65536;            // 65536
    unsigned short* ff1t = opt  + 65536;                // 262144
    unsigned short* ff2t = ff1t + 262144;               // 262144

    float* ybuf = (float*)seg1;
    float* tok1 = (float*)seg1;
    float* xt   = (float*)seg2;
    float* offs = (float*)seg2;
    unsigned short* hid  = (unsigned short*)seg2;
    unsigned short* yt   = (unsigned short*)seg3;
    unsigned short* qhi  = (unsigned short*)seg3;
    unsigned short* hbf  = (unsigned short*)seg3;
    unsigned short* qlo  = (unsigned short*)seg4;
    unsigned short* aggb = (unsigned short*)seg4;

    float* attnP = outp + attn0;

    // ---- all weight conversions, one dispatch ----
    cvt_all_kernel<<<3360, 256, 0, stream>>>(pw_w, op_w, ff1_w, ff2_w, off_w, aw_w,
                                             pwt, opt, ff1t, ff2t, offh, offl, awh, awl);

    // ---- Stage A ----
    dwconv_all_kernel<<<33600, 256, 0, stream>>>(feat[0], feat[1], feat[2], dw_w, dw_b, ybuf);
    for (int l = 0; l < 3; ++l) {
        const int S = SS[l];
        dim3 gt((S + 31) / 32, 8, BATCH);
        transpose_pack_kernel<<<gt, dim3(32, 8, 1), 0, stream>>>(
            ybuf + nchwOff[l], feat[l], yt + (long)rowBase[l] * 256, xt + (long)rowBase[l] * 256, S);
    }
    // fused pointwise: tokens = gelu(y_t @ pw_w[l]^T + pw_b[l]) + x_t  (per-tile LVLSEL)
    {
        dim3 g(2, 263);
        gemm_mfma2<1, true, false, false, true><<<g, 256, 0, stream>>>(
            yt, pwt, pw_b, xt, 256, tokens, 33600, 256, 256, 0);
    }

    // ---- Stage B (fully fused across levels) ----
    ln_all_kernel<1><<<33600, 256, 0, stream>>>(tokens, nq_g, nq_b, lvl_e, qhi, qlo);
    {
        dim3 g(2, 263);
        gemm_split<3><<<g, 256, 0, stream>>>(qhi, qlo, offh, offl, off_b, offs, 33600, 192, 256);
    }
    {
        dim3 g(1, 263);
        gemm_mfma2<0, false, false, false, false><<<g, 256, 0, stream>>>(
            qhi, awh, aw_b, nullptr, 0, attnP, 33600, 96, 256, 0);
    }
    softmax12_kernel<<<(33600 * 8 + 255) / 256, 256, 0, stream>>>(attnP, 33600 * 8);
    sample4_all_kernel<<<8400, 256, 0, stream>>>(offs, attnP, tokens,
                                                 tokens + (long)25600 * 256,
                                                 tokens + (long)32000 * 256, aggb);
    {
        dim3 g(2, 263);
        gemm_mfma2<0, true, false, false, false><<<g, 256, 0, stream>>>(
            aggb, opt, op_b, tokens, 256, tok1, 33600, 256, 256, 0);
    }
    ln_all_kernel<2><<<33600, 256, 0, stream>>>(tok1, nf_g, nf_b, nullptr, hbf, nullptr);
    // FFN in 3 row-chunks (hid overlays dead offs/xt in seg2)
    for (int c0 = 0; c0 < 33600; c0 += 12800) {
        int Mc = 33600 - c0; if (Mc > 12800) Mc = 12800;
        dim3 g1(8, (Mc + 127) / 128);
        gemm_mfma2<2, false, false, true, false><<<g1, 256, 0, stream>>>(
            hbf + (long)c0 * 256, ff1t, ff1_b, nullptr, 0, hid, Mc, 1024, 256, 0);
        dim3 g2(2, (Mc + 127) / 128);
        gemm_mfma2<0, true, true, false, false><<<g2, 256, 0, stream>>>(
            hid, ff2t, ff2_b, tok1 + (long)c0 * 256, 256, outp, Mc, 256, 1024, c0);
    }
}